// Round 2
// baseline (2309.635 us; speedup 1.0000x reference)
//
#include <hip/hip_runtime.h>
#include <hip/hip_bf16.h>

#define N_NODES  20000
#define N_EDGES  320000
#define N_EP     (N_EDGES + N_NODES)
#define D_IN     256
#define N_GRAPHS 32
#define HH1 4
#define CC1 128
#define HH2 4
#define CC2 64

// ---- workspace layout (bytes) ----
#define OUT1_OFF   0ull                       // 20000*512*4 = 40,960,000
#define MENC_OFF   40960000ull                // 20000*4*4   = 320,000
#define DENOM_OFF  41280000ull                // 320,000
#define POOL_OFF   41600000ull                // 32*64*4 = 8192
#define CNT_OFF    41608192ull                // 128
#define EAACC_OFF  41608320ull                // 64 (pad)
#define ZERO0_SIZE 41608384ull                // one contiguous memset
#define H1_OFF     41608448ull                // 40,960,000
#define LOGITS_OFF 82568448ull                // 340000*4*4 = 5,440,000
#define ALS_OFF    88008448ull                // 320,000
#define ALD_OFF    88328448ull                // 320,000
#define MU_OFF     88648448ull                // 2048
#define RSTD_OFF   88650496ull                // 2048
#define SBUF_OFF   88652544ull                // 64
#define FLAG_OFF   88652608ull                // 64
#define XF_OFF     88652672ull                // 20,480,000
#define EAF_OFF    109132672ull               // 1,280,000
#define W1F_OFF    110412672ull               // 524,288
#define W2F_OFF    110936960ull               // 524,288
#define SMALL_OFF  111461248ull               // 25,600
#define H2_OFF     H1_OFF                     // 20000*256*4 (aliases h1)
#define OUT2A_OFF  (H1_OFF + 20480000ull)     // aliases h1 2nd half
#define OUT2_OFF   LOGITS_OFF                 // 20000*64*4 (aliases logits)

// small-region float offsets
#define S_AS1 0
#define S_AD1 512
#define S_WE1 1024
#define S_AE1 1536
#define S_G1  2048
#define S_BE1 2560
#define S_AS2 3072
#define S_AD2 3328
#define S_WE2 3584
#define S_AE2 3840
#define S_G2  4096
#define S_BE2 4160
#define S_FW1 4224
#define S_FB1 6272
#define S_FW2 6304
#define S_FB2 6336

__device__ __forceinline__ unsigned encf(float f) {
    unsigned u = __float_as_uint(f);
    return (u & 0x80000000u) ? ~u : (u | 0x80000000u);
}
__device__ __forceinline__ float decf(unsigned u) {
    return (u & 0x80000000u) ? __uint_as_float(u & 0x7FFFFFFFu) : __uint_as_float(~u);
}

// ---- detect whether float inputs are fp32 (1) or bf16 (0) ----
// true-bf16 data from N(0,1) never has exponent 0xFF; fp32 data read as
// 16-bit halves hits (u&0x7F80)==0x7F80 with P=2^-8 on the mantissa halves.
__global__ void detect_dtype(const unsigned short* __restrict__ xr, int* __restrict__ flag) {
    __shared__ int cnt;
    if (threadIdx.x == 0) cnt = 0;
    __syncthreads();
    int c = 0;
    for (int i = threadIdx.x; i < 65536; i += blockDim.x) {
        unsigned short u = xr[i];
        if ((u & 0x7F80) == 0x7F80) ++c;
    }
    atomicAdd(&cnt, c);
    __syncthreads();
    if (threadIdx.x == 0) flag[0] = (cnt > 0) ? 1 : 0;
}

__device__ __forceinline__ float loadF(const void* p, int i, int fp32) {
    return fp32 ? ((const float*)p)[i]
                : __bfloat162float(((const __hip_bfloat16*)p)[i]);
}

__global__ void cvt_big(const int* __restrict__ flag, const void* __restrict__ src,
                        float* __restrict__ dst, int n) {
    int fp32 = flag[0];
    for (int i = blockIdx.x * blockDim.x + threadIdx.x; i < n; i += gridDim.x * blockDim.x)
        dst[i] = loadF(src, i, fp32);
}

__global__ void cvt_smalls(const int* __restrict__ flag, float* __restrict__ dst,
                           const void* as1, const void* ad1, const void* We1, const void* ae1,
                           const void* g1, const void* be1, const void* as2, const void* ad2,
                           const void* We2, const void* ae2, const void* g2, const void* be2,
                           const void* fw1, const void* fb1, const void* fw2, const void* fb2) {
    const void* srcs[16] = {as1, ad1, We1, ae1, g1, be1, as2, ad2, We2, ae2, g2, be2, fw1, fb1, fw2, fb2};
    const int cnts[16] = {512, 512, 512, 512, 512, 512, 256, 256, 256, 256, 64, 64, 2048, 32, 32, 1};
    const int offs[16] = {S_AS1, S_AD1, S_WE1, S_AE1, S_G1, S_BE1, S_AS2, S_AD2,
                          S_WE2, S_AE2, S_G2, S_BE2, S_FW1, S_FB1, S_FW2, S_FB2};
    int b = blockIdx.x;
    int fp32 = flag[0];
    for (int i = threadIdx.x; i < cnts[b]; i += blockDim.x)
        dst[offs[b] + i] = loadF(srcs[b], i, fp32);
}

// ---- sum(edge_attr) for self-loop fill_value='mean' ----
__global__ void ea_reduce(const float* __restrict__ ea, float* __restrict__ acc) {
    __shared__ float sh[256];
    float s = 0.f;
    for (int i = blockIdx.x * blockDim.x + threadIdx.x; i < N_EDGES; i += gridDim.x * blockDim.x)
        s += ea[i];
    sh[threadIdx.x] = s;
    __syncthreads();
    for (int st = 128; st; st >>= 1) {
        if (threadIdx.x < st) sh[threadIdx.x] += sh[threadIdx.x + st];
        __syncthreads();
    }
    if (threadIdx.x == 0) atomicAdd(acc, sh[0]);
}

// ---- s[h] = sum_c We[h,c]*ae[h,c] for both layers ----
__global__ void compute_s(const float* __restrict__ smalls, float* __restrict__ sbuf) {
    int t = threadIdx.x; // 8 threads: 0-3 layer1, 4-7 layer2
    if (t < 4) {
        float s = 0.f;
        for (int c = 0; c < CC1; ++c) s += smalls[S_WE1 + t * CC1 + c] * smalls[S_AE1 + t * CC1 + c];
        sbuf[t] = s;
    } else if (t < 8) {
        int h = t - 4;
        float s = 0.f;
        for (int c = 0; c < CC2; ++c) s += smalls[S_WE2 + h * CC2 + c] * smalls[S_AE2 + h * CC2 + c];
        sbuf[t] = s;
    }
}

// ---- tiled GEMM C[M,N] = A[M,K] @ B[K,N]; M,N,K all multiples of 16 ----
#define TS 16
__global__ void gemm16(const float* __restrict__ A, const float* __restrict__ B,
                       float* __restrict__ C, int M, int N, int K) {
    __shared__ float As[TS][TS + 1], Bs[TS][TS + 1];
    int tx = threadIdx.x, ty = threadIdx.y;
    int col = blockIdx.x * TS + tx;
    int row = blockIdx.y * TS + ty;
    float acc = 0.f;
    for (int k0 = 0; k0 < K; k0 += TS) {
        As[ty][tx] = A[(size_t)row * K + k0 + tx];
        Bs[ty][tx] = B[(size_t)(k0 + ty) * N + col];
        __syncthreads();
#pragma unroll
        for (int kk = 0; kk < TS; ++kk) acc += As[ty][kk] * Bs[kk][tx];
        __syncthreads();
    }
    C[(size_t)row * N + col] = acc;
}

// ---- al_s[n,h], al_d[n,h] : one wave per node ----
__global__ void al_kernel(const float* __restrict__ hbuf, const float* __restrict__ smalls,
                          int s_as, int s_ad,
                          float* __restrict__ als, float* __restrict__ ald, int H, int C) {
    int n = blockIdx.x;
    int lane = threadIdx.x;
    int HC = H * C;
    for (int h = 0; h < H; ++h) {
        float ss = 0.f, sd = 0.f;
        for (int c = lane; c < C; c += 64) {
            float v = hbuf[(size_t)n * HC + h * C + c];
            ss += v * smalls[s_as + h * C + c];
            sd += v * smalls[s_ad + h * C + c];
        }
        for (int off = 32; off; off >>= 1) {
            ss += __shfl_down(ss, off);
            sd += __shfl_down(sd, off);
        }
        if (lane == 0) { als[n * H + h] = ss; ald[n * H + h] = sd; }
    }
}

// ---- edge logits + leaky_relu + segment max (encoded atomicMax) ----
__global__ void edge_logits_max(const int* __restrict__ ei, const float* __restrict__ ea,
                                const float* __restrict__ ea_acc,
                                const float* __restrict__ als, const float* __restrict__ ald,
                                const float* __restrict__ sbuf,
                                float* __restrict__ logits, unsigned* __restrict__ menc, int H) {
    int e = blockIdx.x * blockDim.x + threadIdx.x;
    if (e >= N_EP) return;
    int s, d;
    float eav;
    if (e < N_EDGES) {
        s = ei[e]; d = ei[N_EDGES + e];
        eav = ea[e];
    } else {
        s = d = e - N_EDGES;
        eav = ea_acc[0] * (1.0f / N_EDGES);
    }
    for (int h = 0; h < H; ++h) {
        float lg = als[s * H + h] + ald[d * H + h] + eav * sbuf[h];
        lg = lg > 0.f ? lg : 0.2f * lg;
        logits[(size_t)e * H + h] = lg;
        atomicMax(&menc[d * H + h], encf(lg));
    }
}

// ---- p = exp(logit - m[dst]); denom += p ----
__global__ void edge_exp_sum(const int* __restrict__ ei, float* __restrict__ logits,
                             const unsigned* __restrict__ menc, float* __restrict__ denom, int H) {
    int e = blockIdx.x * blockDim.x + threadIdx.x;
    if (e >= N_EP) return;
    int d = (e < N_EDGES) ? ei[N_EDGES + e] : e - N_EDGES;
    for (int h = 0; h < H; ++h) {
        float p = expf(logits[(size_t)e * H + h] - decf(menc[d * H + h]));
        logits[(size_t)e * H + h] = p;
        atomicAdd(&denom[d * H + h], p);
    }
}

// ---- out[dst] += h[src] * alpha : one block per edge ----
__global__ void aggregate(const int* __restrict__ ei, const float* __restrict__ hbuf,
                          const float* __restrict__ logits, const float* __restrict__ denom,
                          float* __restrict__ outb, int H, int C) {
    int e = blockIdx.x;
    int s, d;
    if (e < N_EDGES) { s = ei[e]; d = ei[N_EDGES + e]; }
    else { s = d = e - N_EDGES; }
    int HC = H * C;
    for (int i = threadIdx.x; i < HC; i += blockDim.x) {
        int h = i / C;
        float alpha = logits[(size_t)e * H + h] / (denom[d * H + h] + 1e-16f);
        atomicAdd(&outb[(size_t)d * HC + i], hbuf[(size_t)s * HC + i] * alpha);
    }
}

// ---- per-channel mean / rstd over nodes ----
__global__ void bn_stats(const float* __restrict__ x, float* __restrict__ mu, float* __restrict__ rstd, int Cc) {
    int j = blockIdx.x;
    __shared__ float sh[256], sh2[256];
    float s = 0.f, s2 = 0.f;
    for (int i = threadIdx.x; i < N_NODES; i += blockDim.x) {
        float v = x[(size_t)i * Cc + j];
        s += v;
        s2 += v * v;
    }
    sh[threadIdx.x] = s; sh2[threadIdx.x] = s2;
    __syncthreads();
    for (int st = 128; st; st >>= 1) {
        if (threadIdx.x < st) { sh[threadIdx.x] += sh[threadIdx.x + st]; sh2[threadIdx.x] += sh2[threadIdx.x + st]; }
        __syncthreads();
    }
    if (threadIdx.x == 0) {
        float m = sh[0] / N_NODES;
        float var = sh2[0] / N_NODES - m * m;
        mu[j] = m;
        rstd[j] = rsqrtf(var + 1e-5f);
    }
}

// ---- y = elu(gamma*(x-mu)*rstd + beta), in place ----
__global__ void bn_apply_elu(float* __restrict__ x, const float* __restrict__ mu, const float* __restrict__ rstd,
                             const float* __restrict__ smalls, int s_g, int s_be,
                             int total, int Cc) {
    int i = blockIdx.x * blockDim.x + threadIdx.x;
    if (i >= total) return;
    int j = i % Cc;
    float y = smalls[s_g + j] * (x[i] - mu[j]) * rstd[j] + smalls[s_be + j];
    x[i] = y > 0.f ? y : expm1f(y);
}

// ---- mean over heads ----
__global__ void head_mean(const float* __restrict__ ina, float* __restrict__ outb) {
    int i = blockIdx.x * blockDim.x + threadIdx.x;
    if (i >= N_NODES * CC2) return;
    int nd = i / CC2, c = i % CC2;
    float s = 0.f;
#pragma unroll
    for (int h = 0; h < HH2; ++h) s += ina[(size_t)nd * (HH2 * CC2) + h * CC2 + c];
    outb[i] = s * (1.0f / HH2);
}

// ---- mean pool by graph ----
__global__ void pool_kernel(const float* __restrict__ x, const int* __restrict__ batch,
                            float* __restrict__ pooled, float* __restrict__ cnt) {
    int nd = blockIdx.x;
    int c = threadIdx.x; // 64
    int g = batch[nd];
    atomicAdd(&pooled[g * CC2 + c], x[(size_t)nd * CC2 + c]);
    if (c == 0) atomicAdd(&cnt[g], 1.0f);
}

// ---- final MLP: elu(pooled@fw1+fb1)@fw2+fb2 ; out dtype follows detected flag ----
__global__ void mlp_kernel(const float* __restrict__ pooled, const float* __restrict__ cnt,
                           const float* __restrict__ smalls, const int* __restrict__ flag,
                           void* __restrict__ outp) {
    int g = blockIdx.x;
    int k = threadIdx.x; // 32
    __shared__ float hsh[32];
    float ic = 1.0f / fmaxf(cnt[g], 1.0f);
    float acc = smalls[S_FB1 + k];
    for (int c = 0; c < CC2; ++c)
        acc += pooled[g * CC2 + c] * ic * smalls[S_FW1 + c * 32 + k];
    acc = acc > 0.f ? acc : expm1f(acc);
    hsh[k] = acc;
    __syncthreads();
    if (k == 0) {
        float o = smalls[S_FB2];
        for (int t = 0; t < 32; ++t) o += hsh[t] * smalls[S_FW2 + t];
        if (flag[0]) ((float*)outp)[g] = o;
        else ((__hip_bfloat16*)outp)[g] = __float2bfloat16(o);
    }
}

extern "C" void kernel_launch(void* const* d_in, const int* in_sizes, int n_in,
                              void* d_out, int out_size, void* d_ws, size_t ws_size,
                              hipStream_t stream) {
    const void* x   = d_in[0];
    const int* ei   = (const int*)d_in[1];
    const int* batch = (const int*)d_in[2];
    const void* ea  = d_in[3];
    const void* W1  = d_in[4];
    const void* as1 = d_in[5];
    const void* ad1 = d_in[6];
    const void* We1 = d_in[7];
    const void* ae1 = d_in[8];
    const void* g1  = d_in[10];
    const void* be1 = d_in[11];
    const void* W2  = d_in[12];
    const void* as2 = d_in[13];
    const void* ad2 = d_in[14];
    const void* We2 = d_in[15];
    const void* ae2 = d_in[16];
    const void* g2  = d_in[18];
    const void* be2 = d_in[19];
    const void* fw1 = d_in[20];
    const void* fb1 = d_in[21];
    const void* fw2 = d_in[22];
    const void* fb2 = d_in[23];

    char* ws = (char*)d_ws;
    float* out1    = (float*)(ws + OUT1_OFF);
    unsigned* menc = (unsigned*)(ws + MENC_OFF);
    float* denom   = (float*)(ws + DENOM_OFF);
    float* pooled  = (float*)(ws + POOL_OFF);
    float* cnt     = (float*)(ws + CNT_OFF);
    float* ea_acc  = (float*)(ws + EAACC_OFF);
    float* h1      = (float*)(ws + H1_OFF);
    float* logits  = (float*)(ws + LOGITS_OFF);
    float* als     = (float*)(ws + ALS_OFF);
    float* ald     = (float*)(ws + ALD_OFF);
    float* mu      = (float*)(ws + MU_OFF);
    float* rstd    = (float*)(ws + RSTD_OFF);
    float* sbuf    = (float*)(ws + SBUF_OFF);
    int*   flag    = (int*)(ws + FLAG_OFF);
    float* xf      = (float*)(ws + XF_OFF);
    float* eaf     = (float*)(ws + EAF_OFF);
    float* W1f     = (float*)(ws + W1F_OFF);
    float* W2f     = (float*)(ws + W2F_OFF);
    float* smalls  = (float*)(ws + SMALL_OFF);
    float* h2      = (float*)(ws + H2_OFF);
    float* out2a   = (float*)(ws + OUT2A_OFF);
    float* out2    = (float*)(ws + OUT2_OFF);

    // zero: out1 | menc | denom | pooled | cnt | ea_acc  (contiguous)
    hipMemsetAsync(ws, 0, ZERO0_SIZE, stream);

    // ---- dtype detect + convert everything to fp32 ----
    detect_dtype<<<1, 256, 0, stream>>>((const unsigned short*)x, flag);
    cvt_big<<<8192, 256, 0, stream>>>(flag, x, xf, N_NODES * D_IN);
    cvt_big<<<1250, 256, 0, stream>>>(flag, ea, eaf, N_EDGES);
    cvt_big<<<512, 256, 0, stream>>>(flag, W1, W1f, D_IN * HH1 * CC1);
    cvt_big<<<512, 256, 0, stream>>>(flag, W2, W2f, HH1 * CC1 * HH2 * CC2);
    cvt_smalls<<<16, 256, 0, stream>>>(flag, smalls, as1, ad1, We1, ae1, g1, be1,
                                       as2, ad2, We2, ae2, g2, be2, fw1, fb1, fw2, fb2);

    ea_reduce<<<256, 256, 0, stream>>>(eaf, ea_acc);
    compute_s<<<1, 64, 0, stream>>>(smalls, sbuf);

    // ---------- layer 1 ----------
    gemm16<<<dim3(512 / TS, N_NODES / TS), dim3(TS, TS), 0, stream>>>(
        xf, W1f, h1, N_NODES, 512, 256);
    al_kernel<<<N_NODES, 64, 0, stream>>>(h1, smalls, S_AS1, S_AD1, als, ald, HH1, CC1);

    int eb = (N_EP + 255) / 256;
    edge_logits_max<<<eb, 256, 0, stream>>>(ei, eaf, ea_acc, als, ald, sbuf, logits, menc, HH1);
    edge_exp_sum<<<eb, 256, 0, stream>>>(ei, logits, menc, denom, HH1);
    aggregate<<<N_EP, 128, 0, stream>>>(ei, h1, logits, denom, out1, HH1, CC1);

    bn_stats<<<512, 256, 0, stream>>>(out1, mu, rstd, 512);
    bn_apply_elu<<<(N_NODES * 512 + 255) / 256, 256, 0, stream>>>(out1, mu, rstd, smalls, S_G1, S_BE1, N_NODES * 512, 512);

    // ---------- layer 2 ----------
    gemm16<<<dim3(256 / TS, N_NODES / TS), dim3(TS, TS), 0, stream>>>(
        out1, W2f, h2, N_NODES, 256, 512);
    al_kernel<<<N_NODES, 64, 0, stream>>>(h2, smalls, S_AS2, S_AD2, als, ald, HH2, CC2);

    // re-zero segment-max/denoms and the layer-2 accumulator
    hipMemsetAsync(ws + MENC_OFF, 0, 640000, stream);
    hipMemsetAsync(ws + OUT2A_OFF, 0, 20480000, stream);

    edge_logits_max<<<eb, 256, 0, stream>>>(ei, eaf, ea_acc, als, ald, sbuf + 4, logits, menc, HH2);
    edge_exp_sum<<<eb, 256, 0, stream>>>(ei, logits, menc, denom, HH2);
    aggregate<<<N_EP, 128, 0, stream>>>(ei, h2, logits, denom, out2a, HH2, CC2);

    head_mean<<<(N_NODES * CC2 + 255) / 256, 256, 0, stream>>>(out2a, out2);
    bn_stats<<<64, 256, 0, stream>>>(out2, mu, rstd, 64);
    bn_apply_elu<<<(N_NODES * 64 + 255) / 256, 256, 0, stream>>>(out2, mu, rstd, smalls, S_G2, S_BE2, N_NODES * 64, 64);

    // ---------- pool + MLP ----------
    pool_kernel<<<N_NODES, 64, 0, stream>>>(out2, batch, pooled, cnt);
    mlp_kernel<<<N_GRAPHS, 32, 0, stream>>>(pooled, cnt, smalls, flag, d_out);
}

// Round 3
// 1197.948 us; speedup vs baseline: 1.9280x; 1.9280x over previous
//
#include <hip/hip_runtime.h>
#include <hip/hip_bf16.h>

#define N_NODES  20000
#define MP       20032            // N_NODES padded to multiple of 64
#define N_EDGES  320000
#define N_EP     (N_EDGES + N_NODES)
#define D_IN     256
#define N_GRAPHS 32
#define HH1 4
#define CC1 128
#define HH2 4
#define CC2 64

// ---- workspace layout (bytes) ----
#define OUT1_OFF   0ull                        // MP*512*4 = 41,025,536
#define H1_OFF     41025536ull                 // MP*512*4
#define XF_OFF     82051072ull                 // MP*256*4 = 20,512,768
#define LOG_OFF    102563840ull                // N_EP*4*4 = 5,440,000
#define EAF_OFF    108003840ull                // 1,280,000
#define W1F_OFF    109283840ull                // 524,288
#define W2F_OFF    109808128ull                // 524,288
#define CSR_OFF    110332416ull                // N_EP*8 = 2,720,000 (int2)
// ---- zeroed-at-start region ----
#define MENC_OFF   113052416ull                // 320,000
#define DENOM_OFF  113372416ull                // 320,000
#define DEG_OFF    113692416ull                // 80,000 (deg, then cursor)
#define MUSUM_OFF  113772416ull                // 2,048
#define M2SUM_OFF  113774464ull                // 2,048
#define POOL_OFF   113776512ull                // 8,192
#define CNT_OFF    113784704ull                // 128
#define EAACC_OFF  113784832ull                // 64
#define ZERO0_START 113052416ull
#define ZERO0_SIZE  732480ull
// ----
#define ROWPTR_OFF 113784896ull                // 80,064
#define ALS_OFF    113864960ull                // 320,000
#define ALD_OFF    114184960ull                // 320,000
#define MU_OFF     114504960ull                // 2,048
#define RSTD_OFF   114507008ull                // 2,048
#define SBUF_OFF   114509056ull                // 64
#define FLAG_OFF   114509120ull                // 64
#define SMALL_OFF  114509184ull                // 25,600
// aliases
#define H2_OFF     H1_OFF                      // MP*256*4
#define OUT2A_OFF  (H1_OFF + 20512768ull)      // 20000*256*4, fits in h1 region
#define OUT2_OFF   LOG_OFF                     // 20000*64*4, logits dead by then

// small-region float offsets
#define S_AS1 0
#define S_AD1 512
#define S_WE1 1024
#define S_AE1 1536
#define S_G1  2048
#define S_BE1 2560
#define S_AS2 3072
#define S_AD2 3328
#define S_WE2 3584
#define S_AE2 3840
#define S_G2  4096
#define S_BE2 4160
#define S_FW1 4224
#define S_FB1 6272
#define S_FW2 6304
#define S_FB2 6336

__device__ __forceinline__ unsigned encf(float f) {
    unsigned u = __float_as_uint(f);
    return (u & 0x80000000u) ? ~u : (u | 0x80000000u);
}
__device__ __forceinline__ float decf(unsigned u) {
    return (u & 0x80000000u) ? __uint_as_float(u & 0x7FFFFFFFu) : __uint_as_float(~u);
}

// ---- detect whether float inputs are fp32 (1) or bf16 (0) ----
__global__ void detect_dtype(const unsigned short* __restrict__ xr, int* __restrict__ flag) {
    __shared__ int cnt;
    if (threadIdx.x == 0) cnt = 0;
    __syncthreads();
    int c = 0;
    for (int i = threadIdx.x; i < 65536; i += blockDim.x) {
        unsigned short u = xr[i];
        if ((u & 0x7F80) == 0x7F80) ++c;
    }
    atomicAdd(&cnt, c);
    __syncthreads();
    if (threadIdx.x == 0) flag[0] = (cnt > 0) ? 1 : 0;
}

__device__ __forceinline__ float loadF(const void* p, int i, int fp32) {
    return fp32 ? ((const float*)p)[i]
                : __bfloat162float(((const __hip_bfloat16*)p)[i]);
}

__global__ void cvt_big(const int* __restrict__ flag, const void* __restrict__ src,
                        float* __restrict__ dst, int n) {
    int fp32 = flag[0];
    for (int i = blockIdx.x * blockDim.x + threadIdx.x; i < n; i += gridDim.x * blockDim.x)
        dst[i] = loadF(src, i, fp32);
}

__global__ void cvt_smalls(const int* __restrict__ flag, float* __restrict__ dst,
                           const void* as1, const void* ad1, const void* We1, const void* ae1,
                           const void* g1, const void* be1, const void* as2, const void* ad2,
                           const void* We2, const void* ae2, const void* g2, const void* be2,
                           const void* fw1, const void* fb1, const void* fw2, const void* fb2) {
    const void* srcs[16] = {as1, ad1, We1, ae1, g1, be1, as2, ad2, We2, ae2, g2, be2, fw1, fb1, fw2, fb2};
    const int cnts[16] = {512, 512, 512, 512, 512, 512, 256, 256, 256, 256, 64, 64, 2048, 32, 32, 1};
    const int offs[16] = {S_AS1, S_AD1, S_WE1, S_AE1, S_G1, S_BE1, S_AS2, S_AD2,
                          S_WE2, S_AE2, S_G2, S_BE2, S_FW1, S_FB1, S_FW2, S_FB2};
    int b = blockIdx.x;
    int fp32 = flag[0];
    for (int i = threadIdx.x; i < cnts[b]; i += blockDim.x)
        dst[offs[b] + i] = loadF(srcs[b], i, fp32);
}

// ---- sum(edge_attr) ----
__global__ void ea_reduce(const float* __restrict__ ea, float* __restrict__ acc) {
    __shared__ float sh[256];
    float s = 0.f;
    for (int i = blockIdx.x * blockDim.x + threadIdx.x; i < N_EDGES; i += gridDim.x * blockDim.x)
        s += ea[i];
    sh[threadIdx.x] = s;
    __syncthreads();
    for (int st = 128; st; st >>= 1) {
        if (threadIdx.x < st) sh[threadIdx.x] += sh[threadIdx.x + st];
        __syncthreads();
    }
    if (threadIdx.x == 0) atomicAdd(acc, sh[0]);
}

// ---- s[h] = sum_c We[h,c]*ae[h,c] ----
__global__ void compute_s(const float* __restrict__ smalls, float* __restrict__ sbuf) {
    int t = threadIdx.x;
    if (t < 4) {
        float s = 0.f;
        for (int c = 0; c < CC1; ++c) s += smalls[S_WE1 + t * CC1 + c] * smalls[S_AE1 + t * CC1 + c];
        sbuf[t] = s;
    } else if (t < 8) {
        int h = t - 4;
        float s = 0.f;
        for (int c = 0; c < CC2; ++c) s += smalls[S_WE2 + h * CC2 + c] * smalls[S_AE2 + h * CC2 + c];
        sbuf[t] = s;
    }
}

// ---- CSR build ----
__global__ void edge_hist(const int* __restrict__ ei, int* __restrict__ deg) {
    int e = blockIdx.x * blockDim.x + threadIdx.x;
    if (e >= N_EP) return;
    int d = (e < N_EDGES) ? ei[N_EDGES + e] : e - N_EDGES;
    atomicAdd(&deg[d], 1);
}

__global__ void deg_scan(const int* __restrict__ deg, int* __restrict__ rowptr) {
    __shared__ int part[256];
    int t = threadIdx.x;
    int lo = t * 79;
    int hi = lo + 79; if (hi > N_NODES) hi = N_NODES; if (lo > N_NODES) lo = N_NODES;
    int s = 0;
    for (int i = lo; i < hi; ++i) s += deg[i];
    part[t] = s;
    __syncthreads();
    for (int off = 1; off < 256; off <<= 1) {
        int u = (t >= off) ? part[t - off] : 0;
        __syncthreads();
        if (t >= off) part[t] += u;
        __syncthreads();
    }
    int run = part[t] - s;   // exclusive prefix of this thread's range
    for (int i = lo; i < hi; ++i) { rowptr[i] = run; run += deg[i]; }
    if (hi == N_NODES && lo < N_NODES) rowptr[N_NODES] = run;
    if (t == 255 && hi < N_NODES) rowptr[N_NODES] = part[255]; // safety (unreachable here)
}

__global__ void edge_scatter(const int* __restrict__ ei, const int* __restrict__ rowptr,
                             int* __restrict__ cursor, int2* __restrict__ csr_se) {
    int e = blockIdx.x * blockDim.x + threadIdx.x;
    if (e >= N_EP) return;
    int s, d;
    if (e < N_EDGES) { s = ei[e]; d = ei[N_EDGES + e]; }
    else { s = d = e - N_EDGES; }
    int pos = rowptr[d] + atomicAdd(&cursor[d], 1);
    csr_se[pos] = make_int2(s, e);
}

// ---- register-blocked GEMM: C[M,N] = A[M,K]@B[K,N], M%64==0, N%64==0, K%16==0 ----
#define BM 64
#define BN 64
#define BK 16
__global__ __launch_bounds__(256) void gemm_rb(const float* __restrict__ A, const float* __restrict__ B,
                                               float* __restrict__ C, int M, int N, int K) {
    __shared__ float As[BK][68];  // [k][m], pad 68 keeps float4 alignment + 2-way banks
    __shared__ float Bs[BK][68];  // [k][n]
    int t = threadIdx.x;
    int tx = t & 15, ty = t >> 4;
    int m0 = blockIdx.y * BM, n0 = blockIdx.x * BN;
    float acc[4][4] = {};
    for (int k0 = 0; k0 < K; k0 += BK) {
        {
            int lin = t * 4;
            int r = lin >> 4;          // /BK
            int kk = lin & 15;         // %BK  -> 0,4,8,12
            const float* ap = &A[(size_t)(m0 + r) * K + k0 + kk];
            float4 v = *(const float4*)ap;
            As[kk][r] = v.x; As[kk + 1][r] = v.y; As[kk + 2][r] = v.z; As[kk + 3][r] = v.w;
        }
        {
            int lin = t * 4;
            int kk = lin >> 6;         // /BN
            int c = lin & 63;          // %BN
            const float* bp = &B[(size_t)(k0 + kk) * N + n0 + c];
            *(float4*)&Bs[kk][c] = *(const float4*)bp;
        }
        __syncthreads();
#pragma unroll
        for (int kk = 0; kk < BK; ++kk) {
            float4 a = *(const float4*)&As[kk][ty * 4];
            float4 b = *(const float4*)&Bs[kk][tx * 4];
            float av[4] = {a.x, a.y, a.z, a.w};
            float bv[4] = {b.x, b.y, b.z, b.w};
#pragma unroll
            for (int i = 0; i < 4; ++i)
#pragma unroll
                for (int j = 0; j < 4; ++j) acc[i][j] += av[i] * bv[j];
        }
        __syncthreads();
    }
#pragma unroll
    for (int i = 0; i < 4; ++i) {
        float4 v = {acc[i][0], acc[i][1], acc[i][2], acc[i][3]};
        *(float4*)&C[(size_t)(m0 + ty * 4 + i) * N + n0 + tx * 4] = v;
    }
}

// ---- al_s, al_d : one wave per node ----
__global__ void al_kernel(const float* __restrict__ hbuf, const float* __restrict__ smalls,
                          int s_as, int s_ad,
                          float* __restrict__ als, float* __restrict__ ald, int H, int C) {
    int n = blockIdx.x;
    int lane = threadIdx.x;
    int HC = H * C;
    for (int h = 0; h < H; ++h) {
        float ss = 0.f, sd = 0.f;
        for (int c = lane; c < C; c += 64) {
            float v = hbuf[(size_t)n * HC + h * C + c];
            ss += v * smalls[s_as + h * C + c];
            sd += v * smalls[s_ad + h * C + c];
        }
        for (int off = 32; off; off >>= 1) {
            ss += __shfl_down(ss, off);
            sd += __shfl_down(sd, off);
        }
        if (lane == 0) { als[n * H + h] = ss; ald[n * H + h] = sd; }
    }
}

// ---- edge logits + leaky_relu + segment max ----
__global__ void edge_logits_max(const int* __restrict__ ei, const float* __restrict__ ea,
                                const float* __restrict__ ea_acc,
                                const float* __restrict__ als, const float* __restrict__ ald,
                                const float* __restrict__ sbuf,
                                float* __restrict__ logits, unsigned* __restrict__ menc, int H) {
    int e = blockIdx.x * blockDim.x + threadIdx.x;
    if (e >= N_EP) return;
    int s, d;
    float eav;
    if (e < N_EDGES) {
        s = ei[e]; d = ei[N_EDGES + e];
        eav = ea[e];
    } else {
        s = d = e - N_EDGES;
        eav = ea_acc[0] * (1.0f / N_EDGES);
    }
    for (int h = 0; h < H; ++h) {
        float lg = als[s * H + h] + ald[d * H + h] + eav * sbuf[h];
        lg = lg > 0.f ? lg : 0.2f * lg;
        logits[(size_t)e * H + h] = lg;
        atomicMax(&menc[d * H + h], encf(lg));
    }
}

// ---- p = exp(logit - m[dst]); denom += p ----
__global__ void edge_exp_sum(const int* __restrict__ ei, float* __restrict__ logits,
                             const unsigned* __restrict__ menc, float* __restrict__ denom, int H) {
    int e = blockIdx.x * blockDim.x + threadIdx.x;
    if (e >= N_EP) return;
    int d = (e < N_EDGES) ? ei[N_EDGES + e] : e - N_EDGES;
    for (int h = 0; h < H; ++h) {
        float p = expf(logits[(size_t)e * H + h] - decf(menc[d * H + h]));
        logits[(size_t)e * H + h] = p;
        atomicAdd(&denom[d * H + h], p);
    }
}

// ---- CSR aggregation: one block per dst node, no atomics ----
template <int HC, int C, int PC>
__global__ __launch_bounds__(256) void agg_csr(const int* __restrict__ rowptr, const int2* __restrict__ csr_se,
                                               const float* __restrict__ logits, const float* __restrict__ denom,
                                               const float* __restrict__ hbuf, float* __restrict__ outb) {
    constexpr int H = HC / C;
    int d = blockIdx.x;
    int t = threadIdx.x;
    float rdn[H];
#pragma unroll
    for (int h = 0; h < H; ++h) rdn[h] = 1.0f / (denom[d * H + h] + 1e-16f);
    float acc[PC];
#pragma unroll
    for (int pc = 0; pc < PC; ++pc) acc[pc] = 0.f;
    int beg = rowptr[d], end = rowptr[d + 1];
    for (int p = beg; p < end; ++p) {
        int2 se = csr_se[p];
        size_t srow = (size_t)se.x * HC;
        size_t lrow = (size_t)se.y * H;
#pragma unroll
        for (int pc = 0; pc < PC; ++pc) {
            int c = t + pc * 256;
            int h = c / C;
            float w = logits[lrow + h] * rdn[h];
            acc[pc] += w * hbuf[srow + c];
        }
    }
#pragma unroll
    for (int pc = 0; pc < PC; ++pc) outb[(size_t)d * HC + t + pc * 256] = acc[pc];
}

// ---- BN: coalesced partial sums + finalize (finalize self-zeroes partials) ----
__global__ void bn_part(const float* __restrict__ x, float* __restrict__ musum, float* __restrict__ m2sum, int Cc) {
    int c = threadIdx.x;   // blockDim == Cc
    float s = 0.f, s2 = 0.f;
    for (int i = blockIdx.x; i < N_NODES; i += gridDim.x) {
        float v = x[(size_t)i * Cc + c];
        s += v; s2 += v * v;
    }
    atomicAdd(&musum[c], s);
    atomicAdd(&m2sum[c], s2);
}

__global__ void bn_fin(float* __restrict__ musum, float* __restrict__ m2sum,
                       float* __restrict__ mu, float* __restrict__ rstd, int Cc) {
    int c = threadIdx.x;
    if (c >= Cc) return;
    float m = musum[c] / N_NODES;
    float var = m2sum[c] / N_NODES - m * m;
    mu[c] = m;
    rstd[c] = rsqrtf(var + 1e-5f);
    musum[c] = 0.f;
    m2sum[c] = 0.f;
}

__global__ void bn_apply_elu(float* __restrict__ x, const float* __restrict__ mu, const float* __restrict__ rstd,
                             const float* __restrict__ smalls, int s_g, int s_be,
                             int total, int Cc) {
    int i = blockIdx.x * blockDim.x + threadIdx.x;
    if (i >= total) return;
    int j = i % Cc;
    float y = smalls[s_g + j] * (x[i] - mu[j]) * rstd[j] + smalls[s_be + j];
    x[i] = y > 0.f ? y : expm1f(y);
}

// ---- mean over heads ----
__global__ void head_mean(const float* __restrict__ ina, float* __restrict__ outb) {
    int i = blockIdx.x * blockDim.x + threadIdx.x;
    if (i >= N_NODES * CC2) return;
    int nd = i / CC2, c = i % CC2;
    float s = 0.f;
#pragma unroll
    for (int h = 0; h < HH2; ++h) s += ina[(size_t)nd * (HH2 * CC2) + h * CC2 + c];
    outb[i] = s * (1.0f / HH2);
}

// ---- mean pool by graph ----
__global__ void pool_kernel(const float* __restrict__ x, const int* __restrict__ batch,
                            float* __restrict__ pooled, float* __restrict__ cnt) {
    int nd = blockIdx.x;
    int c = threadIdx.x; // 64
    int g = batch[nd];
    atomicAdd(&pooled[g * CC2 + c], x[(size_t)nd * CC2 + c]);
    if (c == 0) atomicAdd(&cnt[g], 1.0f);
}

// ---- final MLP ----
__global__ void mlp_kernel(const float* __restrict__ pooled, const float* __restrict__ cnt,
                           const float* __restrict__ smalls, const int* __restrict__ flag,
                           void* __restrict__ outp) {
    int g = blockIdx.x;
    int k = threadIdx.x; // 32
    __shared__ float hsh[32];
    float ic = 1.0f / fmaxf(cnt[g], 1.0f);
    float acc = smalls[S_FB1 + k];
    for (int c = 0; c < CC2; ++c)
        acc += pooled[g * CC2 + c] * ic * smalls[S_FW1 + c * 32 + k];
    acc = acc > 0.f ? acc : expm1f(acc);
    hsh[k] = acc;
    __syncthreads();
    if (k == 0) {
        float o = smalls[S_FB2];
        for (int t = 0; t < 32; ++t) o += hsh[t] * smalls[S_FW2 + t];
        if (flag[0]) ((float*)outp)[g] = o;
        else ((__hip_bfloat16*)outp)[g] = __float2bfloat16(o);
    }
}

extern "C" void kernel_launch(void* const* d_in, const int* in_sizes, int n_in,
                              void* d_out, int out_size, void* d_ws, size_t ws_size,
                              hipStream_t stream) {
    const void* x    = d_in[0];
    const int* ei    = (const int*)d_in[1];
    const int* batch = (const int*)d_in[2];
    const void* ea   = d_in[3];
    const void* W1   = d_in[4];
    const void* as1  = d_in[5];
    const void* ad1  = d_in[6];
    const void* We1  = d_in[7];
    const void* ae1  = d_in[8];
    const void* g1   = d_in[10];
    const void* be1  = d_in[11];
    const void* W2   = d_in[12];
    const void* as2  = d_in[13];
    const void* ad2  = d_in[14];
    const void* We2  = d_in[15];
    const void* ae2  = d_in[16];
    const void* g2   = d_in[18];
    const void* be2  = d_in[19];
    const void* fw1  = d_in[20];
    const void* fb1  = d_in[21];
    const void* fw2  = d_in[22];
    const void* fb2  = d_in[23];

    char* ws = (char*)d_ws;
    float* out1    = (float*)(ws + OUT1_OFF);
    float* h1      = (float*)(ws + H1_OFF);
    float* xf      = (float*)(ws + XF_OFF);
    float* logits  = (float*)(ws + LOG_OFF);
    float* eaf     = (float*)(ws + EAF_OFF);
    float* W1f     = (float*)(ws + W1F_OFF);
    float* W2f     = (float*)(ws + W2F_OFF);
    int2*  csr_se  = (int2*)(ws + CSR_OFF);
    unsigned* menc = (unsigned*)(ws + MENC_OFF);
    float* denom   = (float*)(ws + DENOM_OFF);
    int*   deg     = (int*)(ws + DEG_OFF);      // deg, then cursor
    float* musum   = (float*)(ws + MUSUM_OFF);
    float* m2sum   = (float*)(ws + M2SUM_OFF);
    float* pooled  = (float*)(ws + POOL_OFF);
    float* cnt     = (float*)(ws + CNT_OFF);
    float* ea_acc  = (float*)(ws + EAACC_OFF);
    int*   rowptr  = (int*)(ws + ROWPTR_OFF);
    float* als     = (float*)(ws + ALS_OFF);
    float* ald     = (float*)(ws + ALD_OFF);
    float* mu      = (float*)(ws + MU_OFF);
    float* rstd    = (float*)(ws + RSTD_OFF);
    float* sbuf    = (float*)(ws + SBUF_OFF);
    int*   flag    = (int*)(ws + FLAG_OFF);
    float* smalls  = (float*)(ws + SMALL_OFF);
    float* h2      = (float*)(ws + H2_OFF);
    float* out2a   = (float*)(ws + OUT2A_OFF);
    float* out2    = (float*)(ws + OUT2_OFF);

    // zero control buffers + pad rows
    hipMemsetAsync(ws + ZERO0_START, 0, ZERO0_SIZE, stream);
    hipMemsetAsync(ws + XF_OFF + 20480000ull, 0, 32768, stream);     // xf pad rows
    hipMemsetAsync(ws + OUT1_OFF + 40960000ull, 0, 65536, stream);   // out1 pad rows

    // dtype detect + fp32 conversion
    detect_dtype<<<1, 256, 0, stream>>>((const unsigned short*)x, flag);
    cvt_big<<<8192, 256, 0, stream>>>(flag, x, xf, N_NODES * D_IN);
    cvt_big<<<1250, 256, 0, stream>>>(flag, ea, eaf, N_EDGES);
    cvt_big<<<512, 256, 0, stream>>>(flag, W1, W1f, D_IN * HH1 * CC1);
    cvt_big<<<512, 256, 0, stream>>>(flag, W2, W2f, HH1 * CC1 * HH2 * CC2);
    cvt_smalls<<<16, 256, 0, stream>>>(flag, smalls, as1, ad1, We1, ae1, g1, be1,
                                       as2, ad2, We2, ae2, g2, be2, fw1, fb1, fw2, fb2);

    ea_reduce<<<256, 256, 0, stream>>>(eaf, ea_acc);
    compute_s<<<1, 64, 0, stream>>>(smalls, sbuf);

    // CSR build (shared by both layers)
    int eb = (N_EP + 255) / 256;
    edge_hist<<<eb, 256, 0, stream>>>(ei, deg);
    deg_scan<<<1, 256, 0, stream>>>(deg, rowptr);
    hipMemsetAsync(ws + DEG_OFF, 0, 80000, stream);                  // deg -> cursor
    edge_scatter<<<eb, 256, 0, stream>>>(ei, rowptr, deg, csr_se);

    // ---------- layer 1 ----------
    gemm_rb<<<dim3(512 / BN, MP / BM), 256, 0, stream>>>(xf, W1f, h1, MP, 512, 256);
    al_kernel<<<N_NODES, 64, 0, stream>>>(h1, smalls, S_AS1, S_AD1, als, ald, HH1, CC1);
    edge_logits_max<<<eb, 256, 0, stream>>>(ei, eaf, ea_acc, als, ald, sbuf, logits, menc, HH1);
    edge_exp_sum<<<eb, 256, 0, stream>>>(ei, logits, menc, denom, HH1);
    agg_csr<512, 128, 2><<<N_NODES, 256, 0, stream>>>(rowptr, csr_se, logits, denom, h1, out1);

    bn_part<<<256, 512, 0, stream>>>(out1, musum, m2sum, 512);
    bn_fin<<<1, 512, 0, stream>>>(musum, m2sum, mu, rstd, 512);
    bn_apply_elu<<<(N_NODES * 512 + 255) / 256, 256, 0, stream>>>(out1, mu, rstd, smalls, S_G1, S_BE1, N_NODES * 512, 512);

    // ---------- layer 2 ----------
    gemm_rb<<<dim3(256 / BN, MP / BM), 256, 0, stream>>>(out1, W2f, h2, MP, 256, 512);
    al_kernel<<<N_NODES, 64, 0, stream>>>(h2, smalls, S_AS2, S_AD2, als, ald, HH2, CC2);

    hipMemsetAsync(ws + MENC_OFF, 0, 640000, stream);                // menc + denom
    edge_logits_max<<<eb, 256, 0, stream>>>(ei, eaf, ea_acc, als, ald, sbuf + 4, logits, menc, HH2);
    edge_exp_sum<<<eb, 256, 0, stream>>>(ei, logits, menc, denom, HH2);
    agg_csr<256, 64, 1><<<N_NODES, 256, 0, stream>>>(rowptr, csr_se, logits, denom, h2, out2a);

    head_mean<<<(N_NODES * CC2 + 255) / 256, 256, 0, stream>>>(out2a, out2);
    bn_part<<<256, 64, 0, stream>>>(out2, musum, m2sum, 64);
    bn_fin<<<1, 64, 0, stream>>>(musum, m2sum, mu, rstd, 64);
    bn_apply_elu<<<(N_NODES * 64 + 255) / 256, 256, 0, stream>>>(out2, mu, rstd, smalls, S_G2, S_BE2, N_NODES * 64, 64);

    // ---------- pool + MLP ----------
    pool_kernel<<<N_NODES, 64, 0, stream>>>(out2, batch, pooled, cnt);
    mlp_kernel<<<N_GRAPHS, 32, 0, stream>>>(pooled, cnt, smalls, flag, d_out);
}

// Round 4
// 1031.201 us; speedup vs baseline: 2.2398x; 1.1617x over previous
//
#include <hip/hip_runtime.h>
#include <hip/hip_bf16.h>

#define N_NODES  20000
#define MP       20032            // N_NODES padded to multiple of 64
#define N_EDGES  320000
#define N_EP     (N_EDGES + N_NODES)
#define D_IN     256
#define N_GRAPHS 32
#define HH1 4
#define CC1 128
#define HH2 4
#define CC2 64

// ---- workspace layout (bytes) ----
#define OUT1_OFF   0ull                        // MP*512*4 = 41,025,536
#define H1_OFF     41025536ull                 // MP*512*4
#define XF_OFF     82051072ull                 // MP*256*4 = 20,512,768
#define LOG_OFF    102563840ull                // N_EP*4*4 = 5,440,000
#define EAF_OFF    108003840ull                // 1,280,000
#define W1F_OFF    109283840ull                // 524,288
#define W2F_OFF    109808128ull                // 524,288
#define CSR_OFF    110332416ull                // N_EP*8 = 2,720,000 (int2)
// ---- zeroed-at-start region ----
#define MENC_OFF   113052416ull                // 320,000
#define DENOM_OFF  113372416ull                // 320,000
#define DEG_OFF    113692416ull                // 80,000 (deg -> cursor -> gstart)
#define MUSUM_OFF  113772416ull                // 2,048
#define M2SUM_OFF  113774464ull                // 2,048
#define POOL_OFF   113776512ull                // 8,192
#define CNT_OFF    113784704ull                // 128 (unused now)
#define EAACC_OFF  113784832ull                // 64
#define ZERO0_START 113052416ull
#define ZERO0_SIZE  732480ull
// ----
#define ROWPTR_OFF 113784896ull                // 80,064
#define ALS_OFF    113864960ull                // 320,000
#define ALD_OFF    114184960ull                // 320,000
#define MU_OFF     114504960ull                // 2,048
#define RSTD_OFF   114507008ull                // 2,048
#define SBUF_OFF   114509056ull                // 64
#define FLAG_OFF   114509120ull                // 64
#define SMALL_OFF  114509184ull                // 25,600
// aliases
#define H2_OFF     H1_OFF                      // MP*256*4
#define OUT2A_OFF  (H1_OFF + 20512768ull)      // 20000*256*4, fits in h1 region
#define OUT2_OFF   LOG_OFF                     // 20000*64*4, logits dead by then

// small-region float offsets
#define S_AS1 0
#define S_AD1 512
#define S_WE1 1024
#define S_AE1 1536
#define S_G1  2048
#define S_BE1 2560
#define S_AS2 3072
#define S_AD2 3328
#define S_WE2 3584
#define S_AE2 3840
#define S_G2  4096
#define S_BE2 4160
#define S_FW1 4224
#define S_FB1 6272
#define S_FW2 6304
#define S_FB2 6336

__device__ __forceinline__ unsigned encf(float f) {
    unsigned u = __float_as_uint(f);
    return (u & 0x80000000u) ? ~u : (u | 0x80000000u);
}
__device__ __forceinline__ float decf(unsigned u) {
    return (u & 0x80000000u) ? __uint_as_float(u & 0x7FFFFFFFu) : __uint_as_float(~u);
}

// ---- detect whether float inputs are fp32 (1) or bf16 (0) ----
__global__ void detect_dtype(const unsigned short* __restrict__ xr, int* __restrict__ flag) {
    __shared__ int cnt;
    if (threadIdx.x == 0) cnt = 0;
    __syncthreads();
    int c = 0;
    for (int i = threadIdx.x; i < 65536; i += blockDim.x) {
        unsigned short u = xr[i];
        if ((u & 0x7F80) == 0x7F80) ++c;
    }
    atomicAdd(&cnt, c);
    __syncthreads();
    if (threadIdx.x == 0) flag[0] = (cnt > 0) ? 1 : 0;
}

__device__ __forceinline__ float loadF(const void* p, int i, int fp32) {
    return fp32 ? ((const float*)p)[i]
                : __bfloat162float(((const __hip_bfloat16*)p)[i]);
}

__global__ void cvt_big(const int* __restrict__ flag, const void* __restrict__ src,
                        float* __restrict__ dst, int n) {
    int fp32 = flag[0];
    for (int i = blockIdx.x * blockDim.x + threadIdx.x; i < n; i += gridDim.x * blockDim.x)
        dst[i] = loadF(src, i, fp32);
}

__global__ void cvt_smalls(const int* __restrict__ flag, float* __restrict__ dst,
                           const void* as1, const void* ad1, const void* We1, const void* ae1,
                           const void* g1, const void* be1, const void* as2, const void* ad2,
                           const void* We2, const void* ae2, const void* g2, const void* be2,
                           const void* fw1, const void* fb1, const void* fw2, const void* fb2) {
    const void* srcs[16] = {as1, ad1, We1, ae1, g1, be1, as2, ad2, We2, ae2, g2, be2, fw1, fb1, fw2, fb2};
    const int cnts[16] = {512, 512, 512, 512, 512, 512, 256, 256, 256, 256, 64, 64, 2048, 32, 32, 1};
    const int offs[16] = {S_AS1, S_AD1, S_WE1, S_AE1, S_G1, S_BE1, S_AS2, S_AD2,
                          S_WE2, S_AE2, S_G2, S_BE2, S_FW1, S_FB1, S_FW2, S_FB2};
    int b = blockIdx.x;
    int fp32 = flag[0];
    for (int i = threadIdx.x; i < cnts[b]; i += blockDim.x)
        dst[offs[b] + i] = loadF(srcs[b], i, fp32);
}

// ---- sum(edge_attr) ----
__global__ void ea_reduce(const float* __restrict__ ea, float* __restrict__ acc) {
    __shared__ float sh[256];
    float s = 0.f;
    for (int i = blockIdx.x * blockDim.x + threadIdx.x; i < N_EDGES; i += gridDim.x * blockDim.x)
        s += ea[i];
    sh[threadIdx.x] = s;
    __syncthreads();
    for (int st = 128; st; st >>= 1) {
        if (threadIdx.x < st) sh[threadIdx.x] += sh[threadIdx.x + st];
        __syncthreads();
    }
    if (threadIdx.x == 0) atomicAdd(acc, sh[0]);
}

// ---- s[h] = sum_c We[h,c]*ae[h,c] ----
__global__ void compute_s(const float* __restrict__ smalls, float* __restrict__ sbuf) {
    int t = threadIdx.x;
    if (t < 4) {
        float s = 0.f;
        for (int c = 0; c < CC1; ++c) s += smalls[S_WE1 + t * CC1 + c] * smalls[S_AE1 + t * CC1 + c];
        sbuf[t] = s;
    } else if (t < 8) {
        int h = t - 4;
        float s = 0.f;
        for (int c = 0; c < CC2; ++c) s += smalls[S_WE2 + h * CC2 + c] * smalls[S_AE2 + h * CC2 + c];
        sbuf[t] = s;
    }
}

// ---- CSR build ----
__global__ void edge_hist(const int* __restrict__ ei, int* __restrict__ deg) {
    int e = blockIdx.x * blockDim.x + threadIdx.x;
    if (e >= N_EP) return;
    int d = (e < N_EDGES) ? ei[N_EDGES + e] : e - N_EDGES;
    atomicAdd(&deg[d], 1);
}

__global__ void deg_scan(const int* __restrict__ deg, int* __restrict__ rowptr) {
    __shared__ int part[256];
    int t = threadIdx.x;
    int lo = t * 79;
    int hi = lo + 79; if (hi > N_NODES) hi = N_NODES; if (lo > N_NODES) lo = N_NODES;
    int s = 0;
    for (int i = lo; i < hi; ++i) s += deg[i];
    part[t] = s;
    __syncthreads();
    for (int off = 1; off < 256; off <<= 1) {
        int u = (t >= off) ? part[t - off] : 0;
        __syncthreads();
        if (t >= off) part[t] += u;
        __syncthreads();
    }
    int run = part[t] - s;   // exclusive prefix of this thread's range
    for (int i = lo; i < hi; ++i) { rowptr[i] = run; run += deg[i]; }
    if (hi == N_NODES && lo < N_NODES) rowptr[N_NODES] = run;
}

__global__ void edge_scatter(const int* __restrict__ ei, const int* __restrict__ rowptr,
                             int* __restrict__ cursor, int2* __restrict__ csr_se) {
    int e = blockIdx.x * blockDim.x + threadIdx.x;
    if (e >= N_EP) return;
    int s, d;
    if (e < N_EDGES) { s = ei[e]; d = ei[N_EDGES + e]; }
    else { s = d = e - N_EDGES; }
    int pos = rowptr[d] + atomicAdd(&cursor[d], 1);
    csr_se[pos] = make_int2(s, e);
}

// ---- graph segment bounds from sorted batch ----
__global__ void graph_bounds(const int* __restrict__ batch, int* __restrict__ gstart) {
    int i = blockIdx.x * blockDim.x + threadIdx.x;
    if (i >= N_NODES) return;
    int b = batch[i];
    if (i == 0) {
        for (int g = 0; g <= b; ++g) gstart[g] = 0;
    } else {
        int pb = batch[i - 1];
        for (int g = pb + 1; g <= b; ++g) gstart[g] = i;
    }
    if (i == N_NODES - 1) {
        for (int g = b + 1; g <= N_GRAPHS; ++g) gstart[g] = N_NODES;
    }
}

// ---- register-blocked GEMM: C[M,N] = A[M,K]@B[K,N], M%64==0, N%64==0, K%16==0 ----
#define BM 64
#define BN 64
#define BK 16
__global__ __launch_bounds__(256) void gemm_rb(const float* __restrict__ A, const float* __restrict__ B,
                                               float* __restrict__ C, int M, int N, int K) {
    __shared__ float As[BK][68];
    __shared__ float Bs[BK][68];
    int t = threadIdx.x;
    int tx = t & 15, ty = t >> 4;
    int m0 = blockIdx.y * BM, n0 = blockIdx.x * BN;
    float acc[4][4] = {};
    for (int k0 = 0; k0 < K; k0 += BK) {
        {
            int lin = t * 4;
            int r = lin >> 4;
            int kk = lin & 15;
            const float* ap = &A[(size_t)(m0 + r) * K + k0 + kk];
            float4 v = *(const float4*)ap;
            As[kk][r] = v.x; As[kk + 1][r] = v.y; As[kk + 2][r] = v.z; As[kk + 3][r] = v.w;
        }
        {
            int lin = t * 4;
            int kk = lin >> 6;
            int c = lin & 63;
            const float* bp = &B[(size_t)(k0 + kk) * N + n0 + c];
            *(float4*)&Bs[kk][c] = *(const float4*)bp;
        }
        __syncthreads();
#pragma unroll
        for (int kk = 0; kk < BK; ++kk) {
            float4 a = *(const float4*)&As[kk][ty * 4];
            float4 b = *(const float4*)&Bs[kk][tx * 4];
            float av[4] = {a.x, a.y, a.z, a.w};
            float bv[4] = {b.x, b.y, b.z, b.w};
#pragma unroll
            for (int i = 0; i < 4; ++i)
#pragma unroll
                for (int j = 0; j < 4; ++j) acc[i][j] += av[i] * bv[j];
        }
        __syncthreads();
    }
#pragma unroll
    for (int i = 0; i < 4; ++i) {
        float4 v = {acc[i][0], acc[i][1], acc[i][2], acc[i][3]};
        *(float4*)&C[(size_t)(m0 + ty * 4 + i) * N + n0 + tx * 4] = v;
    }
}

// ---- al_s, al_d : one wave per node ----
__global__ void al_kernel(const float* __restrict__ hbuf, const float* __restrict__ smalls,
                          int s_as, int s_ad,
                          float* __restrict__ als, float* __restrict__ ald, int H, int C) {
    int n = blockIdx.x;
    int lane = threadIdx.x;
    int HC = H * C;
    for (int h = 0; h < H; ++h) {
        float ss = 0.f, sd = 0.f;
        for (int c = lane; c < C; c += 64) {
            float v = hbuf[(size_t)n * HC + h * C + c];
            ss += v * smalls[s_as + h * C + c];
            sd += v * smalls[s_ad + h * C + c];
        }
        for (int off = 32; off; off >>= 1) {
            ss += __shfl_down(ss, off);
            sd += __shfl_down(sd, off);
        }
        if (lane == 0) { als[n * H + h] = ss; ald[n * H + h] = sd; }
    }
}

// ---- edge logits + leaky_relu + segment max ----
__global__ void edge_logits_max(const int* __restrict__ ei, const float* __restrict__ ea,
                                const float* __restrict__ ea_acc,
                                const float* __restrict__ als, const float* __restrict__ ald,
                                const float* __restrict__ sbuf,
                                float* __restrict__ logits, unsigned* __restrict__ menc, int H) {
    int e = blockIdx.x * blockDim.x + threadIdx.x;
    if (e >= N_EP) return;
    int s, d;
    float eav;
    if (e < N_EDGES) {
        s = ei[e]; d = ei[N_EDGES + e];
        eav = ea[e];
    } else {
        s = d = e - N_EDGES;
        eav = ea_acc[0] * (1.0f / N_EDGES);
    }
    for (int h = 0; h < H; ++h) {
        float lg = als[s * H + h] + ald[d * H + h] + eav * sbuf[h];
        lg = lg > 0.f ? lg : 0.2f * lg;
        logits[(size_t)e * H + h] = lg;
        atomicMax(&menc[d * H + h], encf(lg));
    }
}

// ---- p = exp(logit - m[dst]); denom += p ----
__global__ void edge_exp_sum(const int* __restrict__ ei, float* __restrict__ logits,
                             const unsigned* __restrict__ menc, float* __restrict__ denom, int H) {
    int e = blockIdx.x * blockDim.x + threadIdx.x;
    if (e >= N_EP) return;
    int d = (e < N_EDGES) ? ei[N_EDGES + e] : e - N_EDGES;
    for (int h = 0; h < H; ++h) {
        float p = expf(logits[(size_t)e * H + h] - decf(menc[d * H + h]));
        logits[(size_t)e * H + h] = p;
        atomicAdd(&denom[d * H + h], p);
    }
}

// ---- CSR aggregation: one block per dst node, no atomics ----
template <int HC, int C, int PC>
__global__ __launch_bounds__(256) void agg_csr(const int* __restrict__ rowptr, const int2* __restrict__ csr_se,
                                               const float* __restrict__ logits, const float* __restrict__ denom,
                                               const float* __restrict__ hbuf, float* __restrict__ outb) {
    constexpr int H = HC / C;
    int d = blockIdx.x;
    int t = threadIdx.x;
    float rdn[H];
#pragma unroll
    for (int h = 0; h < H; ++h) rdn[h] = 1.0f / (denom[d * H + h] + 1e-16f);
    float acc[PC];
#pragma unroll
    for (int pc = 0; pc < PC; ++pc) acc[pc] = 0.f;
    int beg = rowptr[d], end = rowptr[d + 1];
    for (int p = beg; p < end; ++p) {
        int2 se = csr_se[p];
        size_t srow = (size_t)se.x * HC;
        size_t lrow = (size_t)se.y * H;
#pragma unroll
        for (int pc = 0; pc < PC; ++pc) {
            int c = t + pc * 256;
            int h = c / C;
            float w = logits[lrow + h] * rdn[h];
            acc[pc] += w * hbuf[srow + c];
        }
    }
#pragma unroll
    for (int pc = 0; pc < PC; ++pc) outb[(size_t)d * HC + t + pc * 256] = acc[pc];
}

// ---- BN: coalesced partial sums + finalize ----
__global__ void bn_part(const float* __restrict__ x, float* __restrict__ musum, float* __restrict__ m2sum, int Cc) {
    int c = threadIdx.x;
    float s = 0.f, s2 = 0.f;
    for (int i = blockIdx.x; i < N_NODES; i += gridDim.x) {
        float v = x[(size_t)i * Cc + c];
        s += v; s2 += v * v;
    }
    atomicAdd(&musum[c], s);
    atomicAdd(&m2sum[c], s2);
}

__global__ void bn_fin(float* __restrict__ musum, float* __restrict__ m2sum,
                       float* __restrict__ mu, float* __restrict__ rstd, int Cc) {
    int c = threadIdx.x;
    if (c >= Cc) return;
    float m = musum[c] / N_NODES;
    float var = m2sum[c] / N_NODES - m * m;
    mu[c] = m;
    rstd[c] = rsqrtf(var + 1e-5f);
    musum[c] = 0.f;
    m2sum[c] = 0.f;
}

__global__ void bn_apply_elu(float* __restrict__ x, const float* __restrict__ mu, const float* __restrict__ rstd,
                             const float* __restrict__ smalls, int s_g, int s_be,
                             int total, int Cc) {
    int i = blockIdx.x * blockDim.x + threadIdx.x;
    if (i >= total) return;
    int j = i % Cc;
    float y = smalls[s_g + j] * (x[i] - mu[j]) * rstd[j] + smalls[s_be + j];
    x[i] = y > 0.f ? y : expm1f(y);
}

// ---- mean over heads ----
__global__ void head_mean(const float* __restrict__ ina, float* __restrict__ outb) {
    int i = blockIdx.x * blockDim.x + threadIdx.x;
    if (i >= N_NODES * CC2) return;
    int nd = i / CC2, c = i % CC2;
    float s = 0.f;
#pragma unroll
    for (int h = 0; h < HH2; ++h) s += ina[(size_t)nd * (HH2 * CC2) + h * CC2 + c];
    outb[i] = s * (1.0f / HH2);
}

// ---- segmented mean pool: one block per graph, no atomics ----
__global__ __launch_bounds__(256) void pool_seg(const float* __restrict__ x, const int* __restrict__ gstart,
                                                float* __restrict__ pooled) {
    int g = blockIdx.x;
    int c = threadIdx.x & 63;
    int j = threadIdx.x >> 6;      // 4 node stripes
    int beg = gstart[g], end = gstart[g + 1];
    float s = 0.f;
    for (int i = beg + j; i < end; i += 4)
        s += x[(size_t)i * CC2 + c];
    __shared__ float sh[4][64];
    sh[j][c] = s;
    __syncthreads();
    if (j == 0) {
        float tot = sh[0][c] + sh[1][c] + sh[2][c] + sh[3][c];
        float n = (float)(end - beg);
        pooled[g * CC2 + c] = tot / fmaxf(n, 1.0f);
    }
}

// ---- final MLP (pooled already holds means) ----
__global__ void mlp_kernel(const float* __restrict__ pooled,
                           const float* __restrict__ smalls, const int* __restrict__ flag,
                           void* __restrict__ outp) {
    int g = blockIdx.x;
    int k = threadIdx.x; // 32
    __shared__ float hsh[32];
    float acc = smalls[S_FB1 + k];
    for (int c = 0; c < CC2; ++c)
        acc += pooled[g * CC2 + c] * smalls[S_FW1 + c * 32 + k];
    acc = acc > 0.f ? acc : expm1f(acc);
    hsh[k] = acc;
    __syncthreads();
    if (k == 0) {
        float o = smalls[S_FB2];
        for (int t = 0; t < 32; ++t) o += hsh[t] * smalls[S_FW2 + t];
        if (flag[0]) ((float*)outp)[g] = o;
        else ((__hip_bfloat16*)outp)[g] = __float2bfloat16(o);
    }
}

extern "C" void kernel_launch(void* const* d_in, const int* in_sizes, int n_in,
                              void* d_out, int out_size, void* d_ws, size_t ws_size,
                              hipStream_t stream) {
    const void* x    = d_in[0];
    const int* ei    = (const int*)d_in[1];
    const int* batch = (const int*)d_in[2];
    const void* ea   = d_in[3];
    const void* W1   = d_in[4];
    const void* as1  = d_in[5];
    const void* ad1  = d_in[6];
    const void* We1  = d_in[7];
    const void* ae1  = d_in[8];
    const void* g1   = d_in[10];
    const void* be1  = d_in[11];
    const void* W2   = d_in[12];
    const void* as2  = d_in[13];
    const void* ad2  = d_in[14];
    const void* We2  = d_in[15];
    const void* ae2  = d_in[16];
    const void* g2   = d_in[18];
    const void* be2  = d_in[19];
    const void* fw1  = d_in[20];
    const void* fb1  = d_in[21];
    const void* fw2  = d_in[22];
    const void* fb2  = d_in[23];

    char* ws = (char*)d_ws;
    float* out1    = (float*)(ws + OUT1_OFF);
    float* h1      = (float*)(ws + H1_OFF);
    float* xf      = (float*)(ws + XF_OFF);
    float* logits  = (float*)(ws + LOG_OFF);
    float* eaf     = (float*)(ws + EAF_OFF);
    float* W1f     = (float*)(ws + W1F_OFF);
    float* W2f     = (float*)(ws + W2F_OFF);
    int2*  csr_se  = (int2*)(ws + CSR_OFF);
    unsigned* menc = (unsigned*)(ws + MENC_OFF);
    float* denom   = (float*)(ws + DENOM_OFF);
    int*   deg     = (int*)(ws + DEG_OFF);      // deg -> cursor -> gstart
    float* musum   = (float*)(ws + MUSUM_OFF);
    float* m2sum   = (float*)(ws + M2SUM_OFF);
    float* pooled  = (float*)(ws + POOL_OFF);
    float* ea_acc  = (float*)(ws + EAACC_OFF);
    int*   rowptr  = (int*)(ws + ROWPTR_OFF);
    float* als     = (float*)(ws + ALS_OFF);
    float* ald     = (float*)(ws + ALD_OFF);
    float* mu      = (float*)(ws + MU_OFF);
    float* rstd    = (float*)(ws + RSTD_OFF);
    float* sbuf    = (float*)(ws + SBUF_OFF);
    int*   flag    = (int*)(ws + FLAG_OFF);
    float* smalls  = (float*)(ws + SMALL_OFF);
    float* h2      = (float*)(ws + H2_OFF);
    float* out2a   = (float*)(ws + OUT2A_OFF);
    float* out2    = (float*)(ws + OUT2_OFF);
    int*   gstart  = (int*)(ws + DEG_OFF);      // reuses deg region after edge_scatter

    // zero control buffers + pad rows
    hipMemsetAsync(ws + ZERO0_START, 0, ZERO0_SIZE, stream);
    hipMemsetAsync(ws + XF_OFF + 20480000ull, 0, 32768, stream);     // xf pad rows
    hipMemsetAsync(ws + OUT1_OFF + 40960000ull, 0, 65536, stream);   // out1 pad rows

    // dtype detect + fp32 conversion
    detect_dtype<<<1, 256, 0, stream>>>((const unsigned short*)x, flag);
    cvt_big<<<8192, 256, 0, stream>>>(flag, x, xf, N_NODES * D_IN);
    cvt_big<<<1250, 256, 0, stream>>>(flag, ea, eaf, N_EDGES);
    cvt_big<<<512, 256, 0, stream>>>(flag, W1, W1f, D_IN * HH1 * CC1);
    cvt_big<<<512, 256, 0, stream>>>(flag, W2, W2f, HH1 * CC1 * HH2 * CC2);
    cvt_smalls<<<16, 256, 0, stream>>>(flag, smalls, as1, ad1, We1, ae1, g1, be1,
                                       as2, ad2, We2, ae2, g2, be2, fw1, fb1, fw2, fb2);

    ea_reduce<<<256, 256, 0, stream>>>(eaf, ea_acc);
    compute_s<<<1, 64, 0, stream>>>(smalls, sbuf);

    // CSR build (shared by both layers)
    int eb = (N_EP + 255) / 256;
    edge_hist<<<eb, 256, 0, stream>>>(ei, deg);
    deg_scan<<<1, 256, 0, stream>>>(deg, rowptr);
    hipMemsetAsync(ws + DEG_OFF, 0, 80000, stream);                  // deg -> cursor
    edge_scatter<<<eb, 256, 0, stream>>>(ei, rowptr, deg, csr_se);
    graph_bounds<<<(N_NODES + 255) / 256, 256, 0, stream>>>(batch, gstart);  // deg region now dead

    // ---------- layer 1 ----------
    gemm_rb<<<dim3(512 / BN, MP / BM), 256, 0, stream>>>(xf, W1f, h1, MP, 512, 256);
    al_kernel<<<N_NODES, 64, 0, stream>>>(h1, smalls, S_AS1, S_AD1, als, ald, HH1, CC1);
    edge_logits_max<<<eb, 256, 0, stream>>>(ei, eaf, ea_acc, als, ald, sbuf, logits, menc, HH1);
    edge_exp_sum<<<eb, 256, 0, stream>>>(ei, logits, menc, denom, HH1);
    agg_csr<512, 128, 2><<<N_NODES, 256, 0, stream>>>(rowptr, csr_se, logits, denom, h1, out1);

    bn_part<<<256, 512, 0, stream>>>(out1, musum, m2sum, 512);
    bn_fin<<<1, 512, 0, stream>>>(musum, m2sum, mu, rstd, 512);
    bn_apply_elu<<<(N_NODES * 512 + 255) / 256, 256, 0, stream>>>(out1, mu, rstd, smalls, S_G1, S_BE1, N_NODES * 512, 512);

    // ---------- layer 2 ----------
    gemm_rb<<<dim3(256 / BN, MP / BM), 256, 0, stream>>>(out1, W2f, h2, MP, 256, 512);
    al_kernel<<<N_NODES, 64, 0, stream>>>(h2, smalls, S_AS2, S_AD2, als, ald, HH2, CC2);

    hipMemsetAsync(ws + MENC_OFF, 0, 640000, stream);                // menc + denom
    edge_logits_max<<<eb, 256, 0, stream>>>(ei, eaf, ea_acc, als, ald, sbuf + 4, logits, menc, HH2);
    edge_exp_sum<<<eb, 256, 0, stream>>>(ei, logits, menc, denom, HH2);
    agg_csr<256, 64, 1><<<N_NODES, 256, 0, stream>>>(rowptr, csr_se, logits, denom, h2, out2a);

    head_mean<<<(N_NODES * CC2 + 255) / 256, 256, 0, stream>>>(out2a, out2);
    bn_part<<<256, 64, 0, stream>>>(out2, musum, m2sum, 64);
    bn_fin<<<1, 64, 0, stream>>>(musum, m2sum, mu, rstd, 64);
    bn_apply_elu<<<(N_NODES * 64 + 255) / 256, 256, 0, stream>>>(out2, mu, rstd, smalls, S_G2, S_BE2, N_NODES * 64, 64);

    // ---------- pool + MLP ----------
    pool_seg<<<N_GRAPHS, 256, 0, stream>>>(out2, gstart, pooled);
    mlp_kernel<<<N_GRAPHS, 32, 0, stream>>>(pooled, smalls, flag, d_out);
}

// Round 5
// 649.802 us; speedup vs baseline: 3.5544x; 1.5869x over previous
//
#include <hip/hip_runtime.h>
#include <hip/hip_bf16.h>

#define N_NODES  20000
#define MP       20032            // N_NODES padded to multiple of 64
#define N_EDGES  320000
#define N_EP     (N_EDGES + N_NODES)
#define D_IN     256
#define N_GRAPHS 32
#define HH1 4
#define CC1 128
#define HH2 4
#define CC2 64

// ---- workspace layout (bytes) ----
#define OUT1_OFF   0ull                        // MP*512*4 = 41,025,536
#define H1_OFF     41025536ull                 // MP*512*4
#define XF_OFF     82051072ull                 // MP*256*4 = 20,512,768 (xf, then hb1/hb2)
#define LOG_OFF    102563840ull                // alpha: N_EP*4*4 = 5,440,000
#define EAF_OFF    108003840ull                // 1,280,000
#define W1F_OFF    109283840ull                // 524,288
#define W2F_OFF    109808128ull                // 524,288
#define CSR_OFF    110332416ull                // N_EP*8 = 2,720,000 (int2)
// ---- zeroed-at-start region ----
#define DEG_OFF    113692416ull                // 80,000 (deg -> cursor -> gstart)
#define MUSUM_OFF  113772416ull                // 2,048
#define M2SUM_OFF  113774464ull                // 2,048
#define POOL_OFF   113776512ull                // 8,192
#define FLAGZ_OFF  113784704ull                // 128 (dtype flag, zeroed)
#define EAACC_OFF  113784832ull                // 64
#define ZERO0_START 113692416ull
#define ZERO0_SIZE  92480ull
// ----
#define ROWPTR_OFF 113784896ull                // 80,064
#define ALS_OFF    113864960ull                // 320,000
#define ALD_OFF    114184960ull                // 320,000
#define MU_OFF     114504960ull                // 2,048
#define RSTD_OFF   114507008ull                // 2,048
#define SBUF_OFF   114509056ull                // 64
#define SMALL_OFF  114509184ull                // 25,600
// aliases
#define H2_OFF     H1_OFF                      // MP*256*4
#define OUT2A_OFF  (H1_OFF + 20512768ull)      // 20000*256*4, after h2
#define OUT2_OFF   LOG_OFF                     // 20000*64*4, alpha dead by then
#define HB_OFF     XF_OFF                      // bf16 h copy, xf dead after gemm1

// small-region float offsets
#define S_AS1 0
#define S_AD1 512
#define S_WE1 1024
#define S_AE1 1536
#define S_G1  2048
#define S_BE1 2560
#define S_AS2 3072
#define S_AD2 3328
#define S_WE2 3584
#define S_AE2 3840
#define S_G2  4096
#define S_BE2 4160
#define S_FW1 4224
#define S_FB1 6272
#define S_FW2 6304
#define S_FB2 6336

// ---- detect whether float inputs are fp32 (1) or bf16 (0); flag pre-zeroed ----
__global__ void detect_dtype(const unsigned short* __restrict__ xr, int* __restrict__ flag) {
    int i = blockIdx.x * blockDim.x + threadIdx.x;   // 256x256 = 65536 shorts
    unsigned short u = xr[i];
    if ((u & 0x7F80) == 0x7F80) atomicOr(flag, 1);
}

__device__ __forceinline__ float loadF(const void* p, int i, int fp32) {
    return fp32 ? ((const float*)p)[i]
                : __bfloat162float(((const __hip_bfloat16*)p)[i]);
}

__global__ void cvt_big(const int* __restrict__ flag, const void* __restrict__ src,
                        float* __restrict__ dst, int n) {
    int fp32 = flag[0];
    for (int i = blockIdx.x * blockDim.x + threadIdx.x; i < n; i += gridDim.x * blockDim.x)
        dst[i] = loadF(src, i, fp32);
}

__global__ void cvt_smalls(const int* __restrict__ flag, float* __restrict__ dst,
                           const void* as1, const void* ad1, const void* We1, const void* ae1,
                           const void* g1, const void* be1, const void* as2, const void* ad2,
                           const void* We2, const void* ae2, const void* g2, const void* be2,
                           const void* fw1, const void* fb1, const void* fw2, const void* fb2) {
    const void* srcs[16] = {as1, ad1, We1, ae1, g1, be1, as2, ad2, We2, ae2, g2, be2, fw1, fb1, fw2, fb2};
    const int cnts[16] = {512, 512, 512, 512, 512, 512, 256, 256, 256, 256, 64, 64, 2048, 32, 32, 1};
    const int offs[16] = {S_AS1, S_AD1, S_WE1, S_AE1, S_G1, S_BE1, S_AS2, S_AD2,
                          S_WE2, S_AE2, S_G2, S_BE2, S_FW1, S_FB1, S_FW2, S_FB2};
    int b = blockIdx.x;
    int fp32 = flag[0];
    for (int i = threadIdx.x; i < cnts[b]; i += blockDim.x)
        dst[offs[b] + i] = loadF(srcs[b], i, fp32);
}

// ---- fp32 -> bf16 copy (n % 4 == 0), for the gather-side h copy ----
__global__ void cvt_f2b(const float* __restrict__ src, __hip_bfloat16* __restrict__ dst, int n) {
    int i = (blockIdx.x * blockDim.x + threadIdx.x) * 4;
    if (i >= n) return;
    float4 v = *(const float4*)&src[i];
    __hip_bfloat16 tmp[4];
    tmp[0] = __float2bfloat16(v.x);
    tmp[1] = __float2bfloat16(v.y);
    tmp[2] = __float2bfloat16(v.z);
    tmp[3] = __float2bfloat16(v.w);
    *(uint2*)&dst[i] = *(uint2*)tmp;
}

// ---- sum(edge_attr) ----
__global__ void ea_reduce(const float* __restrict__ ea, float* __restrict__ acc) {
    __shared__ float sh[256];
    float s = 0.f;
    for (int i = blockIdx.x * blockDim.x + threadIdx.x; i < N_EDGES; i += gridDim.x * blockDim.x)
        s += ea[i];
    sh[threadIdx.x] = s;
    __syncthreads();
    for (int st = 128; st; st >>= 1) {
        if (threadIdx.x < st) sh[threadIdx.x] += sh[threadIdx.x + st];
        __syncthreads();
    }
    if (threadIdx.x == 0) atomicAdd(acc, sh[0]);
}

// ---- s[h] = sum_c We[h,c]*ae[h,c] ----
__global__ void compute_s(const float* __restrict__ smalls, float* __restrict__ sbuf) {
    int t = threadIdx.x;
    if (t < 4) {
        float s = 0.f;
        for (int c = 0; c < CC1; ++c) s += smalls[S_WE1 + t * CC1 + c] * smalls[S_AE1 + t * CC1 + c];
        sbuf[t] = s;
    } else if (t < 8) {
        int h = t - 4;
        float s = 0.f;
        for (int c = 0; c < CC2; ++c) s += smalls[S_WE2 + h * CC2 + c] * smalls[S_AE2 + h * CC2 + c];
        sbuf[t] = s;
    }
}

// ---- CSR build ----
__global__ void edge_hist(const int* __restrict__ ei, int* __restrict__ deg) {
    int e = blockIdx.x * blockDim.x + threadIdx.x;
    if (e >= N_EP) return;
    int d = (e < N_EDGES) ? ei[N_EDGES + e] : e - N_EDGES;
    atomicAdd(&deg[d], 1);
}

__global__ void deg_scan(const int* __restrict__ deg, int* __restrict__ rowptr) {
    __shared__ int part[256];
    int t = threadIdx.x;
    int lo = t * 79;
    int hi = lo + 79; if (hi > N_NODES) hi = N_NODES; if (lo > N_NODES) lo = N_NODES;
    int s = 0;
    for (int i = lo; i < hi; ++i) s += deg[i];
    part[t] = s;
    __syncthreads();
    for (int off = 1; off < 256; off <<= 1) {
        int u = (t >= off) ? part[t - off] : 0;
        __syncthreads();
        if (t >= off) part[t] += u;
        __syncthreads();
    }
    int run = part[t] - s;
    for (int i = lo; i < hi; ++i) { rowptr[i] = run; run += deg[i]; }
    if (hi == N_NODES && lo < N_NODES) rowptr[N_NODES] = run;
}

__global__ void edge_scatter(const int* __restrict__ ei, const int* __restrict__ rowptr,
                             int* __restrict__ cursor, int2* __restrict__ csr_se) {
    int e = blockIdx.x * blockDim.x + threadIdx.x;
    if (e >= N_EP) return;
    int s, d;
    if (e < N_EDGES) { s = ei[e]; d = ei[N_EDGES + e]; }
    else { s = d = e - N_EDGES; }
    int pos = rowptr[d] + atomicAdd(&cursor[d], 1);
    csr_se[pos] = make_int2(s, e);
}

// ---- graph segment bounds from sorted batch ----
__global__ void graph_bounds(const int* __restrict__ batch, int* __restrict__ gstart) {
    int i = blockIdx.x * blockDim.x + threadIdx.x;
    if (i >= N_NODES) return;
    int b = batch[i];
    if (i == 0) {
        for (int g = 0; g <= b; ++g) gstart[g] = 0;
    } else {
        int pb = batch[i - 1];
        for (int g = pb + 1; g <= b; ++g) gstart[g] = i;
    }
    if (i == N_NODES - 1) {
        for (int g = b + 1; g <= N_GRAPHS; ++g) gstart[g] = N_NODES;
    }
}

// ---- register-blocked GEMM: C[M,N] = A[M,K]@B[K,N] ----
#define BM 64
#define BN 64
#define BK 16
__global__ __launch_bounds__(256) void gemm_rb(const float* __restrict__ A, const float* __restrict__ B,
                                               float* __restrict__ C, int M, int N, int K) {
    __shared__ float As[BK][68];
    __shared__ float Bs[BK][68];
    int t = threadIdx.x;
    int tx = t & 15, ty = t >> 4;
    int m0 = blockIdx.y * BM, n0 = blockIdx.x * BN;
    float acc[4][4] = {};
    for (int k0 = 0; k0 < K; k0 += BK) {
        {
            int lin = t * 4;
            int r = lin >> 4;
            int kk = lin & 15;
            const float* ap = &A[(size_t)(m0 + r) * K + k0 + kk];
            float4 v = *(const float4*)ap;
            As[kk][r] = v.x; As[kk + 1][r] = v.y; As[kk + 2][r] = v.z; As[kk + 3][r] = v.w;
        }
        {
            int lin = t * 4;
            int kk = lin >> 6;
            int c = lin & 63;
            const float* bp = &B[(size_t)(k0 + kk) * N + n0 + c];
            *(float4*)&Bs[kk][c] = *(const float4*)bp;
        }
        __syncthreads();
#pragma unroll
        for (int kk = 0; kk < BK; ++kk) {
            float4 a = *(const float4*)&As[kk][ty * 4];
            float4 b = *(const float4*)&Bs[kk][tx * 4];
            float av[4] = {a.x, a.y, a.z, a.w};
            float bv[4] = {b.x, b.y, b.z, b.w};
#pragma unroll
            for (int i = 0; i < 4; ++i)
#pragma unroll
                for (int j = 0; j < 4; ++j) acc[i][j] += av[i] * bv[j];
        }
        __syncthreads();
    }
#pragma unroll
    for (int i = 0; i < 4; ++i) {
        float4 v = {acc[i][0], acc[i][1], acc[i][2], acc[i][3]};
        *(float4*)&C[(size_t)(m0 + ty * 4 + i) * N + n0 + tx * 4] = v;
    }
}

// ---- al_s, al_d : one wave per node ----
__global__ void al_kernel(const float* __restrict__ hbuf, const float* __restrict__ smalls,
                          int s_as, int s_ad,
                          float* __restrict__ als, float* __restrict__ ald, int H, int C) {
    int n = blockIdx.x;
    int lane = threadIdx.x;
    int HC = H * C;
    for (int h = 0; h < H; ++h) {
        float ss = 0.f, sd = 0.f;
        for (int c = lane; c < C; c += 64) {
            float v = hbuf[(size_t)n * HC + h * C + c];
            ss += v * smalls[s_as + h * C + c];
            sd += v * smalls[s_ad + h * C + c];
        }
        for (int off = 32; off; off >>= 1) {
            ss += __shfl_down(ss, off);
            sd += __shfl_down(sd, off);
        }
        if (lane == 0) { als[n * H + h] = ss; ald[n * H + h] = sd; }
    }
}

// ---- fused per-dst segment softmax: one wave per node; writes alpha in CSR order ----
__global__ __launch_bounds__(64) void edge_softmax_csr(
        const int* __restrict__ rowptr, const int2* __restrict__ csr_se,
        const float* __restrict__ als, const float* __restrict__ ald,
        const float* __restrict__ eaf, const float* __restrict__ ea_acc,
        const float* __restrict__ sbuf, float* __restrict__ alpha) {
    int d = blockIdx.x;
    int lane = threadIdx.x;
    int beg = rowptr[d], end = rowptr[d + 1];
    float ea_mean = ea_acc[0] * (1.0f / N_EDGES);
    float4 ad = *(const float4*)&ald[d * 4];
    float s0 = sbuf[0], s1 = sbuf[1], s2 = sbuf[2], s3 = sbuf[3];
    float m0 = -INFINITY, m1 = -INFINITY, m2 = -INFINITY, m3 = -INFINITY;
    // pass 1: logits -> alpha buffer, per-lane max
    for (int p = beg + lane; p < end; p += 64) {
        int2 se = csr_se[p];
        float eav = (se.y < N_EDGES) ? eaf[se.y] : ea_mean;
        float4 as = *(const float4*)&als[se.x * 4];
        float l0 = as.x + ad.x + eav * s0; l0 = l0 > 0.f ? l0 : 0.2f * l0;
        float l1 = as.y + ad.y + eav * s1; l1 = l1 > 0.f ? l1 : 0.2f * l1;
        float l2 = as.z + ad.z + eav * s2; l2 = l2 > 0.f ? l2 : 0.2f * l2;
        float l3 = as.w + ad.w + eav * s3; l3 = l3 > 0.f ? l3 : 0.2f * l3;
        float4 lv = {l0, l1, l2, l3};
        *(float4*)&alpha[(size_t)p * 4] = lv;
        m0 = fmaxf(m0, l0); m1 = fmaxf(m1, l1); m2 = fmaxf(m2, l2); m3 = fmaxf(m3, l3);
    }
#pragma unroll
    for (int off = 1; off < 64; off <<= 1) {
        m0 = fmaxf(m0, __shfl_xor(m0, off));
        m1 = fmaxf(m1, __shfl_xor(m1, off));
        m2 = fmaxf(m2, __shfl_xor(m2, off));
        m3 = fmaxf(m3, __shfl_xor(m3, off));
    }
    // pass 2: p = exp(l - m), per-lane sum
    float t0 = 0.f, t1 = 0.f, t2 = 0.f, t3 = 0.f;
    for (int p = beg + lane; p < end; p += 64) {
        float4 lv = *(const float4*)&alpha[(size_t)p * 4];
        lv.x = __expf(lv.x - m0); lv.y = __expf(lv.y - m1);
        lv.z = __expf(lv.z - m2); lv.w = __expf(lv.w - m3);
        *(float4*)&alpha[(size_t)p * 4] = lv;
        t0 += lv.x; t1 += lv.y; t2 += lv.z; t3 += lv.w;
    }
#pragma unroll
    for (int off = 1; off < 64; off <<= 1) {
        t0 += __shfl_xor(t0, off);
        t1 += __shfl_xor(t1, off);
        t2 += __shfl_xor(t2, off);
        t3 += __shfl_xor(t3, off);
    }
    float r0 = 1.0f / (t0 + 1e-16f), r1 = 1.0f / (t1 + 1e-16f);
    float r2 = 1.0f / (t2 + 1e-16f), r3 = 1.0f / (t3 + 1e-16f);
    // pass 3: normalize
    for (int p = beg + lane; p < end; p += 64) {
        float4 lv = *(const float4*)&alpha[(size_t)p * 4];
        lv.x *= r0; lv.y *= r1; lv.z *= r2; lv.w *= r3;
        *(float4*)&alpha[(size_t)p * 4] = lv;
    }
}

// ---- CSR aggregation over bf16 h rows: block = HC/4 threads, 4 ch/thread ----
template <int HC, int C>
__global__ __launch_bounds__(HC / 4) void agg_csr_bf(
        const int* __restrict__ rowptr, const int2* __restrict__ csr_se,
        const float* __restrict__ alpha, const __hip_bfloat16* __restrict__ hb,
        float* __restrict__ outb) {
    int d = blockIdx.x;
    int t = threadIdx.x;
    int h = (4 * t) / C;
    float a0 = 0.f, a1 = 0.f, a2 = 0.f, a3 = 0.f;
    int beg = rowptr[d], end = rowptr[d + 1];
    for (int p = beg; p < end; ++p) {
        int2 se = csr_se[p];
        float w = alpha[(size_t)p * 4 + h];
        uint2 raw = *(const uint2*)&hb[(size_t)se.x * HC + 4 * t];
        a0 += w * __uint_as_float(raw.x << 16);
        a1 += w * __uint_as_float(raw.x & 0xFFFF0000u);
        a2 += w * __uint_as_float(raw.y << 16);
        a3 += w * __uint_as_float(raw.y & 0xFFFF0000u);
    }
    float4 v = {a0, a1, a2, a3};
    *(float4*)&outb[(size_t)d * HC + 4 * t] = v;
}

// ---- BN: coalesced partial sums + finalize ----
__global__ void bn_part(const float* __restrict__ x, float* __restrict__ musum, float* __restrict__ m2sum, int Cc) {
    int c = threadIdx.x;
    float s = 0.f, s2 = 0.f;
    for (int i = blockIdx.x; i < N_NODES; i += gridDim.x) {
        float v = x[(size_t)i * Cc + c];
        s += v; s2 += v * v;
    }
    atomicAdd(&musum[c], s);
    atomicAdd(&m2sum[c], s2);
}

__global__ void bn_fin(float* __restrict__ musum, float* __restrict__ m2sum,
                       float* __restrict__ mu, float* __restrict__ rstd, int Cc) {
    int c = threadIdx.x;
    if (c >= Cc) return;
    float m = musum[c] / N_NODES;
    float var = m2sum[c] / N_NODES - m * m;
    mu[c] = m;
    rstd[c] = rsqrtf(var + 1e-5f);
    musum[c] = 0.f;
    m2sum[c] = 0.f;
}

__global__ void bn_apply_elu(float* __restrict__ x, const float* __restrict__ mu, const float* __restrict__ rstd,
                             const float* __restrict__ smalls, int s_g, int s_be,
                             int total, int Cc) {
    int i = blockIdx.x * blockDim.x + threadIdx.x;
    if (i >= total) return;
    int j = i % Cc;
    float y = smalls[s_g + j] * (x[i] - mu[j]) * rstd[j] + smalls[s_be + j];
    x[i] = y > 0.f ? y : expm1f(y);
}

// ---- mean over heads ----
__global__ void head_mean(const float* __restrict__ ina, float* __restrict__ outb) {
    int i = blockIdx.x * blockDim.x + threadIdx.x;
    if (i >= N_NODES * CC2) return;
    int nd = i / CC2, c = i % CC2;
    float s = 0.f;
#pragma unroll
    for (int h = 0; h < HH2; ++h) s += ina[(size_t)nd * (HH2 * CC2) + h * CC2 + c];
    outb[i] = s * (1.0f / HH2);
}

// ---- segmented mean pool ----
__global__ __launch_bounds__(256) void pool_seg(const float* __restrict__ x, const int* __restrict__ gstart,
                                                float* __restrict__ pooled) {
    int g = blockIdx.x;
    int c = threadIdx.x & 63;
    int j = threadIdx.x >> 6;
    int beg = gstart[g], end = gstart[g + 1];
    float s = 0.f;
    for (int i = beg + j; i < end; i += 4)
        s += x[(size_t)i * CC2 + c];
    __shared__ float sh[4][64];
    sh[j][c] = s;
    __syncthreads();
    if (j == 0) {
        float tot = sh[0][c] + sh[1][c] + sh[2][c] + sh[3][c];
        float n = (float)(end - beg);
        pooled[g * CC2 + c] = tot / fmaxf(n, 1.0f);
    }
}

// ---- final MLP ----
__global__ void mlp_kernel(const float* __restrict__ pooled,
                           const float* __restrict__ smalls, const int* __restrict__ flag,
                           void* __restrict__ outp) {
    int g = blockIdx.x;
    int k = threadIdx.x; // 32
    __shared__ float hsh[32];
    float acc = smalls[S_FB1 + k];
    for (int c = 0; c < CC2; ++c)
        acc += pooled[g * CC2 + c] * smalls[S_FW1 + c * 32 + k];
    acc = acc > 0.f ? acc : expm1f(acc);
    hsh[k] = acc;
    __syncthreads();
    if (k == 0) {
        float o = smalls[S_FB2];
        for (int t = 0; t < 32; ++t) o += hsh[t] * smalls[S_FW2 + t];
        if (flag[0]) ((float*)outp)[g] = o;
        else ((__hip_bfloat16*)outp)[g] = __float2bfloat16(o);
    }
}

extern "C" void kernel_launch(void* const* d_in, const int* in_sizes, int n_in,
                              void* d_out, int out_size, void* d_ws, size_t ws_size,
                              hipStream_t stream) {
    const void* x    = d_in[0];
    const int* ei    = (const int*)d_in[1];
    const int* batch = (const int*)d_in[2];
    const void* ea   = d_in[3];
    const void* W1   = d_in[4];
    const void* as1  = d_in[5];
    const void* ad1  = d_in[6];
    const void* We1  = d_in[7];
    const void* ae1  = d_in[8];
    const void* g1   = d_in[10];
    const void* be1  = d_in[11];
    const void* W2   = d_in[12];
    const void* as2  = d_in[13];
    const void* ad2  = d_in[14];
    const void* We2  = d_in[15];
    const void* ae2  = d_in[16];
    const void* g2   = d_in[18];
    const void* be2  = d_in[19];
    const void* fw1  = d_in[20];
    const void* fb1  = d_in[21];
    const void* fw2  = d_in[22];
    const void* fb2  = d_in[23];

    char* ws = (char*)d_ws;
    float* out1    = (float*)(ws + OUT1_OFF);
    float* h1      = (float*)(ws + H1_OFF);
    float* xf      = (float*)(ws + XF_OFF);
    float* alpha   = (float*)(ws + LOG_OFF);
    float* eaf     = (float*)(ws + EAF_OFF);
    float* W1f     = (float*)(ws + W1F_OFF);
    float* W2f     = (float*)(ws + W2F_OFF);
    int2*  csr_se  = (int2*)(ws + CSR_OFF);
    int*   deg     = (int*)(ws + DEG_OFF);
    float* musum   = (float*)(ws + MUSUM_OFF);
    float* m2sum   = (float*)(ws + M2SUM_OFF);
    float* pooled  = (float*)(ws + POOL_OFF);
    int*   flag    = (int*)(ws + FLAGZ_OFF);
    float* ea_acc  = (float*)(ws + EAACC_OFF);
    int*   rowptr  = (int*)(ws + ROWPTR_OFF);
    float* als     = (float*)(ws + ALS_OFF);
    float* ald     = (float*)(ws + ALD_OFF);
    float* mu      = (float*)(ws + MU_OFF);
    float* rstd    = (float*)(ws + RSTD_OFF);
    float* sbuf    = (float*)(ws + SBUF_OFF);
    float* smalls  = (float*)(ws + SMALL_OFF);
    float* h2      = (float*)(ws + H2_OFF);
    float* out2a   = (float*)(ws + OUT2A_OFF);
    float* out2    = (float*)(ws + OUT2_OFF);
    int*   gstart  = (int*)(ws + DEG_OFF);
    __hip_bfloat16* hb = (__hip_bfloat16*)(ws + HB_OFF);

    // zero control buffers + pad rows
    hipMemsetAsync(ws + ZERO0_START, 0, ZERO0_SIZE, stream);
    hipMemsetAsync(ws + XF_OFF + 20480000ull, 0, 32768, stream);     // xf pad rows
    hipMemsetAsync(ws + OUT1_OFF + 40960000ull, 0, 65536, stream);   // out1 pad rows

    // dtype detect (parallel) + fp32 conversion
    detect_dtype<<<256, 256, 0, stream>>>((const unsigned short*)x, flag);
    cvt_big<<<8192, 256, 0, stream>>>(flag, x, xf, N_NODES * D_IN);
    cvt_big<<<1250, 256, 0, stream>>>(flag, ea, eaf, N_EDGES);
    cvt_big<<<512, 256, 0, stream>>>(flag, W1, W1f, D_IN * HH1 * CC1);
    cvt_big<<<512, 256, 0, stream>>>(flag, W2, W2f, HH1 * CC1 * HH2 * CC2);
    cvt_smalls<<<16, 256, 0, stream>>>(flag, smalls, as1, ad1, We1, ae1, g1, be1,
                                       as2, ad2, We2, ae2, g2, be2, fw1, fb1, fw2, fb2);

    ea_reduce<<<256, 256, 0, stream>>>(eaf, ea_acc);
    compute_s<<<1, 64, 0, stream>>>(smalls, sbuf);

    // CSR build (shared by both layers)
    int eb = (N_EP + 255) / 256;
    edge_hist<<<eb, 256, 0, stream>>>(ei, deg);
    deg_scan<<<1, 256, 0, stream>>>(deg, rowptr);
    hipMemsetAsync(ws + DEG_OFF, 0, 80000, stream);                  // deg -> cursor
    edge_scatter<<<eb, 256, 0, stream>>>(ei, rowptr, deg, csr_se);
    graph_bounds<<<(N_NODES + 255) / 256, 256, 0, stream>>>(batch, gstart);

    // ---------- layer 1 ----------
    gemm_rb<<<dim3(512 / BN, MP / BM), 256, 0, stream>>>(xf, W1f, h1, MP, 512, 256);
    al_kernel<<<N_NODES, 64, 0, stream>>>(h1, smalls, S_AS1, S_AD1, als, ald, HH1, CC1);
    cvt_f2b<<<10000, 256, 0, stream>>>(h1, hb, N_NODES * 512);       // xf dead -> hb1
    edge_softmax_csr<<<N_NODES, 64, 0, stream>>>(rowptr, csr_se, als, ald, eaf, ea_acc, sbuf, alpha);
    agg_csr_bf<512, 128><<<N_NODES, 128, 0, stream>>>(rowptr, csr_se, alpha, hb, out1);

    bn_part<<<256, 512, 0, stream>>>(out1, musum, m2sum, 512);
    bn_fin<<<1, 512, 0, stream>>>(musum, m2sum, mu, rstd, 512);
    bn_apply_elu<<<(N_NODES * 512 + 255) / 256, 256, 0, stream>>>(out1, mu, rstd, smalls, S_G1, S_BE1, N_NODES * 512, 512);

    // ---------- layer 2 ----------
    gemm_rb<<<dim3(256 / BN, MP / BM), 256, 0, stream>>>(out1, W2f, h2, MP, 256, 512);
    al_kernel<<<N_NODES, 64, 0, stream>>>(h2, smalls, S_AS2, S_AD2, als, ald, HH2, CC2);
    cvt_f2b<<<5000, 256, 0, stream>>>(h2, hb, N_NODES * 256);        // hb2
    edge_softmax_csr<<<N_NODES, 64, 0, stream>>>(rowptr, csr_se, als, ald, eaf, ea_acc, sbuf + 4, alpha);
    agg_csr_bf<256, 64><<<N_NODES, 64, 0, stream>>>(rowptr, csr_se, alpha, hb, out2a);

    head_mean<<<(N_NODES * CC2 + 255) / 256, 256, 0, stream>>>(out2a, out2);
    bn_part<<<256, 64, 0, stream>>>(out2, musum, m2sum, 64);
    bn_fin<<<1, 64, 0, stream>>>(musum, m2sum, mu, rstd, 64);
    bn_apply_elu<<<(N_NODES * 64 + 255) / 256, 256, 0, stream>>>(out2, mu, rstd, smalls, S_G2, S_BE2, N_NODES * 64, 64);

    // ---------- pool + MLP ----------
    pool_seg<<<N_GRAPHS, 256, 0, stream>>>(out2, gstart, pooled);
    mlp_kernel<<<N_GRAPHS, 32, 0, stream>>>(pooled, smalls, flag, d_out);
}

// Round 6
// 516.085 us; speedup vs baseline: 4.4753x; 1.2591x over previous
//
#include <hip/hip_runtime.h>
#include <hip/hip_bf16.h>

#define N_NODES  20000
#define MPAD     20096            // padded to multiple of 128
#define N_EDGES  320000
#define N_EP     (N_EDGES + N_NODES)
#define D_IN     256
#define N_GRAPHS 32
#define HH1 4
#define CC1 128
#define HH2 4
#define CC2 64

// ---- workspace layout (bytes) ----
#define R1_OFF     0ull                        // 41,156,608 : h1 -> out1 -> (h2 | hb2)
#define R2_OFF     41156608ull                 // 20,578,304 : hb1 -> out1b -> out2a
#define XB_OFF     61734912ull                 // 10,289,152 : x bf16 [MPAD,256]
#define ALPHA_OFF  72024064ull                 // 5,440,000  : alpha -> out2
#define EAF_OFF    77464064ull                 // 1,280,000
#define W1BT_OFF   78744064ull                 // 262,144 : W1^T bf16 [512,256]
#define W2BT_OFF   79006208ull                 // 262,144 : W2^T bf16 [256,512]
#define CSR_OFF    79268352ull                 // 2,720,000 (int2)
// ---- zeroed-at-start region ----
#define DEG_OFF    81988352ull                 // 80,000 (deg -> cursor -> gstart)
#define MUSUM_OFF  82068352ull                 // 2,048
#define M2SUM_OFF  82070400ull                 // 2,048
#define POOL_OFF   82072448ull                 // 8,192
#define FLAGZ_OFF  82080640ull                 // 128
#define EAACC_OFF  82080768ull                 // 64
#define ZERO0_START DEG_OFF
#define ZERO0_SIZE  92480ull
// ----
#define ROWPTR_OFF 82080832ull                 // 80,064
#define ALS_OFF    82160896ull                 // 320,000
#define ALD_OFF    82480896ull                 // 320,000
#define MU_OFF     82800896ull                 // 2,048
#define RSTD_OFF   82802944ull                 // 2,048
#define SBUF_OFF   82804992ull                 // 64
#define SMALL_OFF  82805056ull                 // 25,600
// aliases
#define H1_OFF     R1_OFF
#define OUT1_OFF   R1_OFF
#define H2_OFF     R1_OFF
#define HB2_OFF    (R1_OFF + 20578304ull)
#define HB1_OFF    R2_OFF
#define OUT1B_OFF  R2_OFF
#define OUT2A_OFF  R2_OFF
#define OUT2_OFF   ALPHA_OFF

// small-region float offsets
#define S_AS1 0
#define S_AD1 512
#define S_WE1 1024
#define S_AE1 1536
#define S_G1  2048
#define S_BE1 2560
#define S_AS2 3072
#define S_AD2 3328
#define S_WE2 3584
#define S_AE2 3840
#define S_G2  4096
#define S_BE2 4160
#define S_FW1 4224
#define S_FB1 6272
#define S_FW2 6304
#define S_FB2 6336

typedef __attribute__((ext_vector_type(8))) short bf8_t;   // 8 bf16 = 4 VGPRs
typedef __attribute__((ext_vector_type(4))) float f4_t;    // 4 fp32

// ---- detect whether float inputs are fp32 (1) or bf16 (0); flag pre-zeroed ----
__global__ void detect_dtype(const unsigned short* __restrict__ xr, int* __restrict__ flag) {
    int i = blockIdx.x * blockDim.x + threadIdx.x;   // 256x256 = 65536 shorts
    unsigned short u = xr[i];
    if ((u & 0x7F80) == 0x7F80) atomicOr(flag, 1);
}

__device__ __forceinline__ float loadF(const void* p, int i, int fp32) {
    return fp32 ? ((const float*)p)[i]
                : __bfloat162float(((const __hip_bfloat16*)p)[i]);
}

__global__ void cvt_big(const int* __restrict__ flag, const void* __restrict__ src,
                        float* __restrict__ dst, int n) {
    int fp32 = flag[0];
    for (int i = blockIdx.x * blockDim.x + threadIdx.x; i < n; i += gridDim.x * blockDim.x)
        dst[i] = loadF(src, i, fp32);
}

// ---- input -> bf16 with zero tail padding ----
__global__ void cvt_to_bf16(const int* __restrict__ flag, const void* __restrict__ src,
                            __hip_bfloat16* __restrict__ dst, int n_valid, int n_total) {
    int i = blockIdx.x * blockDim.x + threadIdx.x;
    if (i >= n_total) return;
    float v = (i < n_valid) ? loadF(src, i, flag[0]) : 0.f;
    dst[i] = __float2bfloat16(v);
}

// ---- weight [K,N] -> transposed bf16 [N,K] ----
__global__ void cvt_w_t(const int* __restrict__ flag, const void* __restrict__ W,
                        __hip_bfloat16* __restrict__ Wt, int K, int N) {
    int i = blockIdx.x * blockDim.x + threadIdx.x;
    if (i >= K * N) return;
    int k = i / N, n = i % N;
    Wt[(size_t)n * K + k] = __float2bfloat16(loadF(W, i, flag[0]));
}

__global__ void cvt_smalls(const int* __restrict__ flag, float* __restrict__ dst,
                           const void* as1, const void* ad1, const void* We1, const void* ae1,
                           const void* g1, const void* be1, const void* as2, const void* ad2,
                           const void* We2, const void* ae2, const void* g2, const void* be2,
                           const void* fw1, const void* fb1, const void* fw2, const void* fb2) {
    const void* srcs[16] = {as1, ad1, We1, ae1, g1, be1, as2, ad2, We2, ae2, g2, be2, fw1, fb1, fw2, fb2};
    const int cnts[16] = {512, 512, 512, 512, 512, 512, 256, 256, 256, 256, 64, 64, 2048, 32, 32, 1};
    const int offs[16] = {S_AS1, S_AD1, S_WE1, S_AE1, S_G1, S_BE1, S_AS2, S_AD2,
                          S_WE2, S_AE2, S_G2, S_BE2, S_FW1, S_FB1, S_FW2, S_FB2};
    int b = blockIdx.x;
    int fp32 = flag[0];
    for (int i = threadIdx.x; i < cnts[b]; i += blockDim.x)
        dst[offs[b] + i] = loadF(srcs[b], i, fp32);
}

// ---- sum(edge_attr) ----
__global__ void ea_reduce(const float* __restrict__ ea, float* __restrict__ acc) {
    __shared__ float sh[256];
    float s = 0.f;
    for (int i = blockIdx.x * blockDim.x + threadIdx.x; i < N_EDGES; i += gridDim.x * blockDim.x)
        s += ea[i];
    sh[threadIdx.x] = s;
    __syncthreads();
    for (int st = 128; st; st >>= 1) {
        if (threadIdx.x < st) sh[threadIdx.x] += sh[threadIdx.x + st];
        __syncthreads();
    }
    if (threadIdx.x == 0) atomicAdd(acc, sh[0]);
}

// ---- s[h] = sum_c We[h,c]*ae[h,c] ----
__global__ void compute_s(const float* __restrict__ smalls, float* __restrict__ sbuf) {
    int t = threadIdx.x;
    if (t < 4) {
        float s = 0.f;
        for (int c = 0; c < CC1; ++c) s += smalls[S_WE1 + t * CC1 + c] * smalls[S_AE1 + t * CC1 + c];
        sbuf[t] = s;
    } else if (t < 8) {
        int h = t - 4;
        float s = 0.f;
        for (int c = 0; c < CC2; ++c) s += smalls[S_WE2 + h * CC2 + c] * smalls[S_AE2 + h * CC2 + c];
        sbuf[t] = s;
    }
}

// ---- CSR build ----
__global__ void edge_hist(const int* __restrict__ ei, int* __restrict__ deg) {
    int e = blockIdx.x * blockDim.x + threadIdx.x;
    if (e >= N_EP) return;
    int d = (e < N_EDGES) ? ei[N_EDGES + e] : e - N_EDGES;
    atomicAdd(&deg[d], 1);
}

__global__ void deg_scan(const int* __restrict__ deg, int* __restrict__ rowptr) {
    __shared__ int part[256];
    int t = threadIdx.x;
    int lo = t * 79;
    int hi = lo + 79; if (hi > N_NODES) hi = N_NODES; if (lo > N_NODES) lo = N_NODES;
    int s = 0;
    for (int i = lo; i < hi; ++i) s += deg[i];
    part[t] = s;
    __syncthreads();
    for (int off = 1; off < 256; off <<= 1) {
        int u = (t >= off) ? part[t - off] : 0;
        __syncthreads();
        if (t >= off) part[t] += u;
        __syncthreads();
    }
    int run = part[t] - s;
    for (int i = lo; i < hi; ++i) { rowptr[i] = run; run += deg[i]; }
    if (hi == N_NODES && lo < N_NODES) rowptr[N_NODES] = run;
}

__global__ void edge_scatter(const int* __restrict__ ei, const int* __restrict__ rowptr,
                             int* __restrict__ cursor, int2* __restrict__ csr_se) {
    int e = blockIdx.x * blockDim.x + threadIdx.x;
    if (e >= N_EP) return;
    int s, d;
    if (e < N_EDGES) { s = ei[e]; d = ei[N_EDGES + e]; }
    else { s = d = e - N_EDGES; }
    int pos = rowptr[d] + atomicAdd(&cursor[d], 1);
    csr_se[pos] = make_int2(s, e);
}

// ---- graph segment bounds from sorted batch ----
__global__ void graph_bounds(const int* __restrict__ batch, int* __restrict__ gstart) {
    int i = blockIdx.x * blockDim.x + threadIdx.x;
    if (i >= N_NODES) return;
    int b = batch[i];
    if (i == 0) {
        for (int g = 0; g <= b; ++g) gstart[g] = 0;
    } else {
        int pb = batch[i - 1];
        for (int g = pb + 1; g <= b; ++g) gstart[g] = i;
    }
    if (i == N_NODES - 1) {
        for (int g = b + 1; g <= N_GRAPHS; ++g) gstart[g] = N_NODES;
    }
}

// ---- MFMA bf16 GEMM: C[M,N](fp32)+Cb(bf16) = A[M,K] @ Bt[N,K]^T ----
// tile 128x64, BK=32, 4 waves; M%128==0, N%64==0, K%32==0
// LDS pitch 40 shorts (80 B): 16B-aligned ds_read_b128, banks spread (20-bank stride)
__global__ __launch_bounds__(256) void gemm_mfma(
        const short* __restrict__ A, const short* __restrict__ Bt,
        float* __restrict__ C, __hip_bfloat16* __restrict__ Cb, int N, int K) {
    __shared__ short As[128 * 40];
    __shared__ short Bs[64 * 40];
    int t = threadIdx.x;
    int wv = t >> 6, lane = t & 63, quad = lane >> 4, lr = lane & 15;
    int m0 = blockIdx.y * 128, n0 = blockIdx.x * 64;
    f4_t acc[2][4] = {};
    int ra0 = t >> 2, sa0 = t & 3;                 // A chunk 0 (= B chunk)
    int ra1 = (t + 256) >> 2, sa1 = t & 3;         // A chunk 1
    for (int k0 = 0; k0 < K; k0 += 32) {
        *(uint4*)&As[ra0 * 40 + sa0 * 8] = *(const uint4*)&A[(size_t)(m0 + ra0) * K + k0 + sa0 * 8];
        *(uint4*)&As[ra1 * 40 + sa1 * 8] = *(const uint4*)&A[(size_t)(m0 + ra1) * K + k0 + sa1 * 8];
        *(uint4*)&Bs[ra0 * 40 + sa0 * 8] = *(const uint4*)&Bt[(size_t)(n0 + ra0) * K + k0 + sa0 * 8];
        __syncthreads();
        bf8_t a0 = *(const bf8_t*)&As[(wv * 16 + lr) * 40 + quad * 8];
        bf8_t a1 = *(const bf8_t*)&As[((wv + 4) * 16 + lr) * 40 + quad * 8];
#pragma unroll
        for (int nt = 0; nt < 4; ++nt) {
            bf8_t b = *(const bf8_t*)&Bs[(nt * 16 + lr) * 40 + quad * 8];
            acc[0][nt] = __builtin_amdgcn_mfma_f32_16x16x32_bf16(a0, b, acc[0][nt], 0, 0, 0);
            acc[1][nt] = __builtin_amdgcn_mfma_f32_16x16x32_bf16(a1, b, acc[1][nt], 0, 0, 0);
        }
        __syncthreads();
    }
#pragma unroll
    for (int si = 0; si < 2; ++si) {
        int mrow = m0 + (wv + si * 4) * 16 + quad * 4;
#pragma unroll
        for (int nt = 0; nt < 4; ++nt) {
            int col = n0 + nt * 16 + lr;
#pragma unroll
            for (int r = 0; r < 4; ++r) {
                float v = acc[si][nt][r];
                C[(size_t)(mrow + r) * N + col] = v;
                Cb[(size_t)(mrow + r) * N + col] = __float2bfloat16(v);
            }
        }
    }
}

// ---- al_s, al_d : one wave per node ----
__global__ void al_kernel(const float* __restrict__ hbuf, const float* __restrict__ smalls,
                          int s_as, int s_ad,
                          float* __restrict__ als, float* __restrict__ ald, int H, int C) {
    int n = blockIdx.x;
    int lane = threadIdx.x;
    int HC = H * C;
    for (int h = 0; h < H; ++h) {
        float ss = 0.f, sd = 0.f;
        for (int c = lane; c < C; c += 64) {
            float v = hbuf[(size_t)n * HC + h * C + c];
            ss += v * smalls[s_as + h * C + c];
            sd += v * smalls[s_ad + h * C + c];
        }
        for (int off = 32; off; off >>= 1) {
            ss += __shfl_down(ss, off);
            sd += __shfl_down(sd, off);
        }
        if (lane == 0) { als[n * H + h] = ss; ald[n * H + h] = sd; }
    }
}

// ---- fused per-dst segment softmax: one wave per node; alpha in CSR order ----
__global__ __launch_bounds__(64) void edge_softmax_csr(
        const int* __restrict__ rowptr, const int2* __restrict__ csr_se,
        const float* __restrict__ als, const float* __restrict__ ald,
        const float* __restrict__ eaf, const float* __restrict__ ea_acc,
        const float* __restrict__ sbuf, float* __restrict__ alpha) {
    int d = blockIdx.x;
    int lane = threadIdx.x;
    int beg = rowptr[d], end = rowptr[d + 1];
    float ea_mean = ea_acc[0] * (1.0f / N_EDGES);
    float4 ad = *(const float4*)&ald[d * 4];
    float s0 = sbuf[0], s1 = sbuf[1], s2 = sbuf[2], s3 = sbuf[3];
    float m0 = -INFINITY, m1 = -INFINITY, m2 = -INFINITY, m3 = -INFINITY;
    for (int p = beg + lane; p < end; p += 64) {
        int2 se = csr_se[p];
        float eav = (se.y < N_EDGES) ? eaf[se.y] : ea_mean;
        float4 as = *(const float4*)&als[se.x * 4];
        float l0 = as.x + ad.x + eav * s0; l0 = l0 > 0.f ? l0 : 0.2f * l0;
        float l1 = as.y + ad.y + eav * s1; l1 = l1 > 0.f ? l1 : 0.2f * l1;
        float l2 = as.z + ad.z + eav * s2; l2 = l2 > 0.f ? l2 : 0.2f * l2;
        float l3 = as.w + ad.w + eav * s3; l3 = l3 > 0.f ? l3 : 0.2f * l3;
        float4 lv = {l0, l1, l2, l3};
        *(float4*)&alpha[(size_t)p * 4] = lv;
        m0 = fmaxf(m0, l0); m1 = fmaxf(m1, l1); m2 = fmaxf(m2, l2); m3 = fmaxf(m3, l3);
    }
#pragma unroll
    for (int off = 1; off < 64; off <<= 1) {
        m0 = fmaxf(m0, __shfl_xor(m0, off));
        m1 = fmaxf(m1, __shfl_xor(m1, off));
        m2 = fmaxf(m2, __shfl_xor(m2, off));
        m3 = fmaxf(m3, __shfl_xor(m3, off));
    }
    float t0 = 0.f, t1 = 0.f, t2 = 0.f, t3 = 0.f;
    for (int p = beg + lane; p < end; p += 64) {
        float4 lv = *(const float4*)&alpha[(size_t)p * 4];
        lv.x = __expf(lv.x - m0); lv.y = __expf(lv.y - m1);
        lv.z = __expf(lv.z - m2); lv.w = __expf(lv.w - m3);
        *(float4*)&alpha[(size_t)p * 4] = lv;
        t0 += lv.x; t1 += lv.y; t2 += lv.z; t3 += lv.w;
    }
#pragma unroll
    for (int off = 1; off < 64; off <<= 1) {
        t0 += __shfl_xor(t0, off);
        t1 += __shfl_xor(t1, off);
        t2 += __shfl_xor(t2, off);
        t3 += __shfl_xor(t3, off);
    }
    float r0 = 1.0f / (t0 + 1e-16f), r1 = 1.0f / (t1 + 1e-16f);
    float r2 = 1.0f / (t2 + 1e-16f), r3 = 1.0f / (t3 + 1e-16f);
    for (int p = beg + lane; p < end; p += 64) {
        float4 lv = *(const float4*)&alpha[(size_t)p * 4];
        lv.x *= r0; lv.y *= r1; lv.z *= r2; lv.w *= r3;
        *(float4*)&alpha[(size_t)p * 4] = lv;
    }
}

// ---- CSR aggregation over bf16 h rows: block = HC/4 threads, 4 ch/thread ----
template <int HC, int C>
__global__ __launch_bounds__(HC / 4) void agg_csr_bf(
        const int* __restrict__ rowptr, const int2* __restrict__ csr_se,
        const float* __restrict__ alpha, const __hip_bfloat16* __restrict__ hb,
        float* __restrict__ outb) {
    int d = blockIdx.x;
    int t = threadIdx.x;
    int h = (4 * t) / C;
    float a0 = 0.f, a1 = 0.f, a2 = 0.f, a3 = 0.f;
    int beg = rowptr[d], end = rowptr[d + 1];
    for (int p = beg; p < end; ++p) {
        int2 se = csr_se[p];
        float w = alpha[(size_t)p * 4 + h];
        uint2 raw = *(const uint2*)&hb[(size_t)se.x * HC + 4 * t];
        a0 += w * __uint_as_float(raw.x << 16);
        a1 += w * __uint_as_float(raw.x & 0xFFFF0000u);
        a2 += w * __uint_as_float(raw.y << 16);
        a3 += w * __uint_as_float(raw.y & 0xFFFF0000u);
    }
    float4 v = {a0, a1, a2, a3};
    *(float4*)&outb[(size_t)d * HC + 4 * t] = v;
}

// ---- BN: coalesced partial sums + finalize ----
__global__ void bn_part(const float* __restrict__ x, float* __restrict__ musum, float* __restrict__ m2sum, int Cc) {
    int c = threadIdx.x;
    float s = 0.f, s2 = 0.f;
    for (int i = blockIdx.x; i < N_NODES; i += gridDim.x) {
        float v = x[(size_t)i * Cc + c];
        s += v; s2 += v * v;
    }
    atomicAdd(&musum[c], s);
    atomicAdd(&m2sum[c], s2);
}

__global__ void bn_fin(float* __restrict__ musum, float* __restrict__ m2sum,
                       float* __restrict__ mu, float* __restrict__ rstd, int Cc) {
    int c = threadIdx.x;
    if (c >= Cc) return;
    float m = musum[c] / N_NODES;
    float var = m2sum[c] / N_NODES - m * m;
    mu[c] = m;
    rstd[c] = rsqrtf(var + 1e-5f);
    musum[c] = 0.f;
    m2sum[c] = 0.f;
}

// ---- BN apply + ELU -> bf16 (feeds gemm2 A operand) ----
__global__ void bn_apply_elu_b(const float* __restrict__ x, const float* __restrict__ mu,
                               const float* __restrict__ rstd, const float* __restrict__ smalls,
                               int s_g, int s_be, __hip_bfloat16* __restrict__ out,
                               int total, int Cc) {
    int i = blockIdx.x * blockDim.x + threadIdx.x;
    if (i >= total) return;
    int j = i % Cc;
    float y = smalls[s_g + j] * (x[i] - mu[j]) * rstd[j] + smalls[s_be + j];
    y = y > 0.f ? y : expm1f(y);
    out[i] = __float2bfloat16(y);
}

// ---- BN apply + ELU fp32 in place ----
__global__ void bn_apply_elu(float* __restrict__ x, const float* __restrict__ mu, const float* __restrict__ rstd,
                             const float* __restrict__ smalls, int s_g, int s_be,
                             int total, int Cc) {
    int i = blockIdx.x * blockDim.x + threadIdx.x;
    if (i >= total) return;
    int j = i % Cc;
    float y = smalls[s_g + j] * (x[i] - mu[j]) * rstd[j] + smalls[s_be + j];
    x[i] = y > 0.f ? y : expm1f(y);
}

// ---- mean over heads ----
__global__ void head_mean(const float* __restrict__ ina, float* __restrict__ outb) {
    int i = blockIdx.x * blockDim.x + threadIdx.x;
    if (i >= N_NODES * CC2) return;
    int nd = i / CC2, c = i % CC2;
    float s = 0.f;
#pragma unroll
    for (int h = 0; h < HH2; ++h) s += ina[(size_t)nd * (HH2 * CC2) + h * CC2 + c];
    outb[i] = s * (1.0f / HH2);
}

// ---- segmented mean pool ----
__global__ __launch_bounds__(256) void pool_seg(const float* __restrict__ x, const int* __restrict__ gstart,
                                                float* __restrict__ pooled) {
    int g = blockIdx.x;
    int c = threadIdx.x & 63;
    int j = threadIdx.x >> 6;
    int beg = gstart[g], end = gstart[g + 1];
    float s = 0.f;
    for (int i = beg + j; i < end; i += 4)
        s += x[(size_t)i * CC2 + c];
    __shared__ float sh[4][64];
    sh[j][c] = s;
    __syncthreads();
    if (j == 0) {
        float tot = sh[0][c] + sh[1][c] + sh[2][c] + sh[3][c];
        float n = (float)(end - beg);
        pooled[g * CC2 + c] = tot / fmaxf(n, 1.0f);
    }
}

// ---- final MLP ----
__global__ void mlp_kernel(const float* __restrict__ pooled,
                           const float* __restrict__ smalls, const int* __restrict__ flag,
                           void* __restrict__ outp) {
    int g = blockIdx.x;
    int k = threadIdx.x; // 32
    __shared__ float hsh[32];
    float acc = smalls[S_FB1 + k];
    for (int c = 0; c < CC2; ++c)
        acc += pooled[g * CC2 + c] * smalls[S_FW1 + c * 32 + k];
    acc = acc > 0.f ? acc : expm1f(acc);
    hsh[k] = acc;
    __syncthreads();
    if (k == 0) {
        float o = smalls[S_FB2];
        for (int t = 0; t < 32; ++t) o += hsh[t] * smalls[S_FW2 + t];
        if (flag[0]) ((float*)outp)[g] = o;
        else ((__hip_bfloat16*)outp)[g] = __float2bfloat16(o);
    }
}

extern "C" void kernel_launch(void* const* d_in, const int* in_sizes, int n_in,
                              void* d_out, int out_size, void* d_ws, size_t ws_size,
                              hipStream_t stream) {
    const void* x    = d_in[0];
    const int* ei    = (const int*)d_in[1];
    const int* batch = (const int*)d_in[2];
    const void* ea   = d_in[3];
    const void* W1   = d_in[4];
    const void* as1  = d_in[5];
    const void* ad1  = d_in[6];
    const void* We1  = d_in[7];
    const void* ae1  = d_in[8];
    const void* g1   = d_in[10];
    const void* be1  = d_in[11];
    const void* W2   = d_in[12];
    const void* as2  = d_in[13];
    const void* ad2  = d_in[14];
    const void* We2  = d_in[15];
    const void* ae2  = d_in[16];
    const void* g2   = d_in[18];
    const void* be2  = d_in[19];
    const void* fw1  = d_in[20];
    const void* fb1  = d_in[21];
    const void* fw2  = d_in[22];
    const void* fb2  = d_in[23];

    char* ws = (char*)d_ws;
    float* h1      = (float*)(ws + H1_OFF);
    float* out1    = (float*)(ws + OUT1_OFF);
    float* h2      = (float*)(ws + H2_OFF);
    __hip_bfloat16* hb1   = (__hip_bfloat16*)(ws + HB1_OFF);
    __hip_bfloat16* hb2   = (__hip_bfloat16*)(ws + HB2_OFF);
    __hip_bfloat16* out1b = (__hip_bfloat16*)(ws + OUT1B_OFF);
    __hip_bfloat16* xb    = (__hip_bfloat16*)(ws + XB_OFF);
    __hip_bfloat16* W1bt  = (__hip_bfloat16*)(ws + W1BT_OFF);
    __hip_bfloat16* W2bt  = (__hip_bfloat16*)(ws + W2BT_OFF);
    float* out2a   = (float*)(ws + OUT2A_OFF);
    float* out2    = (float*)(ws + OUT2_OFF);
    float* alpha   = (float*)(ws + ALPHA_OFF);
    float* eaf     = (float*)(ws + EAF_OFF);
    int2*  csr_se  = (int2*)(ws + CSR_OFF);
    int*   deg     = (int*)(ws + DEG_OFF);
    float* musum   = (float*)(ws + MUSUM_OFF);
    float* m2sum   = (float*)(ws + M2SUM_OFF);
    float* pooled  = (float*)(ws + POOL_OFF);
    int*   flag    = (int*)(ws + FLAGZ_OFF);
    float* ea_acc  = (float*)(ws + EAACC_OFF);
    int*   rowptr  = (int*)(ws + ROWPTR_OFF);
    float* als     = (float*)(ws + ALS_OFF);
    float* ald     = (float*)(ws + ALD_OFF);
    float* mu      = (float*)(ws + MU_OFF);
    float* rstd    = (float*)(ws + RSTD_OFF);
    float* sbuf    = (float*)(ws + SBUF_OFF);
    float* smalls  = (float*)(ws + SMALL_OFF);
    int*   gstart  = (int*)(ws + DEG_OFF);

    // zero control buffers
    hipMemsetAsync(ws + ZERO0_START, 0, ZERO0_SIZE, stream);

    // dtype detect + conversions
    detect_dtype<<<256, 256, 0, stream>>>((const unsigned short*)x, flag);
    cvt_to_bf16<<<(MPAD * D_IN + 255) / 256, 256, 0, stream>>>(flag, x, xb, N_NODES * D_IN, MPAD * D_IN);
    cvt_big<<<1250, 256, 0, stream>>>(flag, ea, eaf, N_EDGES);
    cvt_w_t<<<512, 256, 0, stream>>>(flag, W1, W1bt, D_IN, HH1 * CC1);
    cvt_w_t<<<512, 256, 0, stream>>>(flag, W2, W2bt, HH1 * CC1, HH2 * CC2);
    cvt_smalls<<<16, 256, 0, stream>>>(flag, smalls, as1, ad1, We1, ae1, g1, be1,
                                       as2, ad2, We2, ae2, g2, be2, fw1, fb1, fw2, fb2);

    ea_reduce<<<256, 256, 0, stream>>>(eaf, ea_acc);
    compute_s<<<1, 64, 0, stream>>>(smalls, sbuf);

    // CSR build (shared by both layers)
    int eb = (N_EP + 255) / 256;
    edge_hist<<<eb, 256, 0, stream>>>(ei, deg);
    deg_scan<<<1, 256, 0, stream>>>(deg, rowptr);
    hipMemsetAsync(ws + DEG_OFF, 0, 80000, stream);                  // deg -> cursor
    edge_scatter<<<eb, 256, 0, stream>>>(ei, rowptr, deg, csr_se);
    graph_bounds<<<(N_NODES + 255) / 256, 256, 0, stream>>>(batch, gstart);

    // ---------- layer 1 ----------
    gemm_mfma<<<dim3(512 / 64, MPAD / 128), 256, 0, stream>>>(
        (const short*)xb, (const short*)W1bt, h1, hb1, 512, 256);
    al_kernel<<<N_NODES, 64, 0, stream>>>(h1, smalls, S_AS1, S_AD1, als, ald, HH1, CC1);
    edge_softmax_csr<<<N_NODES, 64, 0, stream>>>(rowptr, csr_se, als, ald, eaf, ea_acc, sbuf, alpha);
    agg_csr_bf<512, 128><<<N_NODES, 128, 0, stream>>>(rowptr, csr_se, alpha, hb1, out1);

    bn_part<<<256, 512, 0, stream>>>(out1, musum, m2sum, 512);
    bn_fin<<<1, 512, 0, stream>>>(musum, m2sum, mu, rstd, 512);
    bn_apply_elu_b<<<(N_NODES * 512 + 255) / 256, 256, 0, stream>>>(
        out1, mu, rstd, smalls, S_G1, S_BE1, out1b, N_NODES * 512, 512);

    // ---------- layer 2 ----------
    gemm_mfma<<<dim3(256 / 64, MPAD / 128), 256, 0, stream>>>(
        (const short*)out1b, (const short*)W2bt, h2, hb2, 256, 512);
    al_kernel<<<N_NODES, 64, 0, stream>>>(h2, smalls, S_AS2, S_AD2, als, ald, HH2, CC2);
    edge_softmax_csr<<<N_NODES, 64, 0, stream>>>(rowptr, csr_se, als, ald, eaf, ea_acc, sbuf + 4, alpha);
    agg_csr_bf<256, 64><<<N_NODES, 64, 0, stream>>>(rowptr, csr_se, alpha, hb2, out2a);

    head_mean<<<(N_NODES * CC2 + 255) / 256, 256, 0, stream>>>(out2a, out2);
    bn_part<<<256, 64, 0, stream>>>(out2, musum, m2sum, 64);
    bn_fin<<<1, 64, 0, stream>>>(musum, m2sum, mu, rstd, 64);
    bn_apply_elu<<<(N_NODES * 64 + 255) / 256, 256, 0, stream>>>(out2, mu, rstd, smalls, S_G2, S_BE2, N_NODES * 64, 64);

    // ---------- pool + MLP ----------
    pool_seg<<<N_GRAPHS, 256, 0, stream>>>(out2, gstart, pooled);
    mlp_kernel<<<N_GRAPHS, 32, 0, stream>>>(pooled, smalls, flag, d_out);
}

// Round 7
// 496.251 us; speedup vs baseline: 4.6542x; 1.0400x over previous
//
#include <hip/hip_runtime.h>
#include <hip/hip_bf16.h>

#define N_NODES  20000
#define MPAD     20096
#define N_EDGES  320000
#define N_EP     (N_EDGES + N_NODES)
#define D_IN     256
#define N_GRAPHS 32
#define HH1 4
#define CC1 128
#define HH2 4
#define CC2 64

// ---- workspace layout (bytes) ----
#define XB_OFF      0ull                    // 10,289,152 : x bf16 [MPAD,256]
#define HB1_OFF     10289152ull             // 20,578,304 : h1 bf16 [MPAD,512]
#define AGG1_OFF    30867456ull             // 20,578,304 : agg1 out bf16 [MPAD,512] (in-place BN)
#define HB2_OFF     51445760ull             // 10,289,152 : h2 bf16 [MPAD,256]
#define OUT2A_OFF   61734912ull             // 20,480,000 : agg2 out fp32 [20000,256]
#define OUT2_OFF    82214912ull             //  5,120,000 : head-mean fp32 [20000,64]
#define ALPHA_OFF   87334912ull             //  5,440,000 : alpha fp32 [N_EP,4]
#define DENOM_OFF   92774912ull             //    320,000
#define EAF_OFF     93094912ull             //  1,280,000
#define W1BT_OFF    94374912ull             //    262,144 : W1^T bf16 [512,256]
#define W2BT_OFF    94637056ull             //    262,144 : W2^T bf16 [256,512]
#define CSR_OFF     94899200ull             //  2,720,000 (int2)
#define ROWPTR_OFF  97619200ull             //     80,064
#define GSTART_OFF  97699264ull             //        256
#define SMALL_OFF   97699520ull             //     25,600
#define SBUF_OFF    97725120ull             //         64
// ---- zeroed-at-start region ----
#define DEG_OFF     97725184ull             //     80,000
#define CURS_OFF    97805184ull             //     80,000
#define ALS1_OFF    97885184ull             //    321,536
#define ALD1_OFF    98206720ull             //    321,536
#define ALS2_OFF    98528256ull             //    321,536
#define ALD2_OFF    98849792ull             //    321,536
#define MUSUM1_OFF  99171328ull             //      2,048
#define M2SUM1_OFF  99173376ull             //      2,048
#define MUSUM2_OFF  99175424ull             //        512
#define M2SUM2_OFF  99175936ull             //        512
#define FLAGZ_OFF   99176448ull             //        128
#define EAACC_OFF   99176576ull             //         64
#define ZERO0_START DEG_OFF
#define ZERO0_SIZE  1451456ull

// small-region float offsets
#define S_AS1 0
#define S_AD1 512
#define S_WE1 1024
#define S_AE1 1536
#define S_G1  2048
#define S_BE1 2560
#define S_AS2 3072
#define S_AD2 3328
#define S_WE2 3584
#define S_AE2 3840
#define S_G2  4096
#define S_BE2 4160
#define S_FW1 4224
#define S_FB1 6272
#define S_FW2 6304
#define S_FB2 6336

typedef __attribute__((ext_vector_type(8))) short bf8_t;
typedef __attribute__((ext_vector_type(4))) float f4_t;

// ---- detect fp32 (1) vs bf16 (0); flag pre-zeroed ----
__global__ void detect_dtype(const unsigned short* __restrict__ xr, int* __restrict__ flag) {
    int i = blockIdx.x * blockDim.x + threadIdx.x;
    unsigned short u = xr[i];
    if ((u & 0x7F80) == 0x7F80) atomicOr(flag, 1);
}

__device__ __forceinline__ float loadF(const void* p, int i, int fp32) {
    return fp32 ? ((const float*)p)[i]
                : __bfloat162float(((const __hip_bfloat16*)p)[i]);
}

// ---- fused prep: xb | eaf+ea_acc | W1t | W2t | smalls | sbuf ----
#define PB_XB  5024
#define PB_EAF 313
#define PB_W   512
#define PB_SM  16
#define PREP_BLOCKS (PB_XB + PB_EAF + 2 * PB_W + PB_SM + 1)
__global__ __launch_bounds__(256) void prep(
        const int* __restrict__ flag,
        const void* x, const void* ea, const void* W1, const void* W2,
        const void* as1, const void* ad1, const void* We1, const void* ae1,
        const void* g1, const void* be1, const void* as2, const void* ad2,
        const void* We2, const void* ae2, const void* g2, const void* be2,
        const void* fw1, const void* fb1, const void* fw2, const void* fb2,
        __hip_bfloat16* __restrict__ xb, float* __restrict__ eaf, float* __restrict__ ea_acc,
        __hip_bfloat16* __restrict__ W1bt, __hip_bfloat16* __restrict__ W2bt,
        float* __restrict__ smalls, float* __restrict__ sbuf) {
    __shared__ float sh[256];
    int b = blockIdx.x, t = threadIdx.x;
    int fp32 = flag[0];
    if (b < PB_XB) {                                   // x -> bf16 [MPAD,256], zero pad
        int base = (b * 256 + t) * 4;
        __hip_bfloat16 tmp[4];
#pragma unroll
        for (int j = 0; j < 4; ++j) {
            int i = base + j;
            float v = (i < N_NODES * D_IN) ? loadF(x, i, fp32) : 0.f;
            tmp[j] = __float2bfloat16(v);
        }
        *(uint2*)&xb[base] = *(uint2*)tmp;
        return;
    }
    b -= PB_XB;
    if (b < PB_EAF) {                                  // ea -> fp32 + sum
        int base = (b * 256 + t) * 4;
        float s = 0.f;
#pragma unroll
        for (int j = 0; j < 4; ++j) {
            int i = base + j;
            if (i < N_EDGES) { float v = loadF(ea, i, fp32); eaf[i] = v; s += v; }
        }
        sh[t] = s;
        __syncthreads();
        for (int st = 128; st; st >>= 1) {
            if (t < st) sh[t] += sh[t + st];
            __syncthreads();
        }
        if (t == 0) atomicAdd(ea_acc, sh[0]);
        return;
    }
    b -= PB_EAF;
    if (b < PB_W) {                                    // W1 [256,512] -> W1bt [512,256]
        int i = b * 256 + t;                           // 131072 total
        int k = i >> 9, n = i & 511;
        W1bt[(size_t)n * 256 + k] = __float2bfloat16(loadF(W1, i, fp32));
        return;
    }
    b -= PB_W;
    if (b < PB_W) {                                    // W2 [512,256] -> W2bt [256,512]
        int i = b * 256 + t;
        int k = i >> 8, n = i & 255;
        W2bt[(size_t)n * 512 + k] = __float2bfloat16(loadF(W2, i, fp32));
        return;
    }
    b -= PB_W;
    if (b < PB_SM) {                                   // smalls
        const void* srcs[16] = {as1, ad1, We1, ae1, g1, be1, as2, ad2, We2, ae2, g2, be2, fw1, fb1, fw2, fb2};
        const int cnts[16] = {512, 512, 512, 512, 512, 512, 256, 256, 256, 256, 64, 64, 2048, 32, 32, 1};
        const int offs[16] = {S_AS1, S_AD1, S_WE1, S_AE1, S_G1, S_BE1, S_AS2, S_AD2,
                              S_WE2, S_AE2, S_G2, S_BE2, S_FW1, S_FB1, S_FW2, S_FB2};
        for (int i = t; i < cnts[b]; i += 256)
            smalls[offs[b] + i] = loadF(srcs[b], i, fp32);
        return;
    }
    // sbuf: s[h] = sum_c We[h,c]*ae[h,c], from raw inputs
    if (t < 4) {
        float s = 0.f;
        for (int c = 0; c < CC1; ++c) s += loadF(We1, t * CC1 + c, fp32) * loadF(ae1, t * CC1 + c, fp32);
        sbuf[t] = s;
    } else if (t < 8) {
        int h = t - 4;
        float s = 0.f;
        for (int c = 0; c < CC2; ++c) s += loadF(We2, h * CC2 + c, fp32) * loadF(ae2, h * CC2 + c, fp32);
        sbuf[4 + h] = s;
    }
}

// ---- fused hist + graph bounds ----
#define HIST_BLOCKS 1329
__global__ void hist_bounds(const int* __restrict__ ei, int* __restrict__ deg,
                            const int* __restrict__ batch, int* __restrict__ gstart) {
    int b = blockIdx.x, t = threadIdx.x;
    if (b < HIST_BLOCKS) {
        int e = b * 256 + t;
        if (e >= N_EP) return;
        int d = (e < N_EDGES) ? ei[N_EDGES + e] : e - N_EDGES;
        atomicAdd(&deg[d], 1);
        return;
    }
    int i = (b - HIST_BLOCKS) * 256 + t;
    if (i >= N_NODES) return;
    int bb = batch[i];
    if (i == 0) {
        for (int g = 0; g <= bb; ++g) gstart[g] = 0;
    } else {
        int pb = batch[i - 1];
        for (int g = pb + 1; g <= bb; ++g) gstart[g] = i;
    }
    if (i == N_NODES - 1) {
        for (int g = bb + 1; g <= N_GRAPHS; ++g) gstart[g] = N_NODES;
    }
}

__global__ __launch_bounds__(1024) void deg_scan(const int* __restrict__ deg, int* __restrict__ rowptr) {
    __shared__ int part[1024];
    int t = threadIdx.x;
    int lo = t * 20;
    int hi = lo + 20; if (hi > N_NODES) hi = N_NODES; if (lo > N_NODES) lo = N_NODES;
    int s = 0;
    for (int i = lo; i < hi; ++i) s += deg[i];
    part[t] = s;
    __syncthreads();
    for (int off = 1; off < 1024; off <<= 1) {
        int u = (t >= off) ? part[t - off] : 0;
        __syncthreads();
        if (t >= off) part[t] += u;
        __syncthreads();
    }
    int run = part[t] - s;
    for (int i = lo; i < hi; ++i) { rowptr[i] = run; run += deg[i]; }
    if (hi == N_NODES && lo < N_NODES) rowptr[N_NODES] = run;
}

__global__ void edge_scatter(const int* __restrict__ ei, const int* __restrict__ rowptr,
                             int* __restrict__ cursor, int2* __restrict__ csr_se) {
    int e = blockIdx.x * blockDim.x + threadIdx.x;
    if (e >= N_EP) return;
    int s, d;
    if (e < N_EDGES) { s = ei[e]; d = ei[N_EDGES + e]; }
    else { s = d = e - N_EDGES; }
    int pos = rowptr[d] + atomicAdd(&cursor[d], 1);
    csr_se[pos] = make_int2(s, e);
}

// ---- MFMA bf16 GEMM + fused al epilogue ----
// Cb(bf16)[MPAD,N] = A[M,K] @ Bt[N,K]^T ; als/ald += per-row dots with asv/adv
__global__ __launch_bounds__(256) void gemm_mfma_al(
        const short* __restrict__ A, const short* __restrict__ Bt,
        __hip_bfloat16* __restrict__ Cb, int N, int K,
        float* __restrict__ als, float* __restrict__ ald,
        const float* __restrict__ asv, const float* __restrict__ adv, int cshift) {
    __shared__ short As[128 * 40];
    __shared__ short Bs[64 * 40];
    int t = threadIdx.x;
    int wv = t >> 6, lane = t & 63, quad = lane >> 4, lr = lane & 15;
    int m0 = blockIdx.y * 128, n0 = blockIdx.x * 64;
    f4_t acc[2][4] = {};
    int ra0 = t >> 2, sa0 = t & 3;
    int ra1 = (t + 256) >> 2;
    for (int k0 = 0; k0 < K; k0 += 32) {
        *(uint4*)&As[ra0 * 40 + sa0 * 8] = *(const uint4*)&A[(size_t)(m0 + ra0) * K + k0 + sa0 * 8];
        *(uint4*)&As[ra1 * 40 + sa0 * 8] = *(const uint4*)&A[(size_t)(m0 + ra1) * K + k0 + sa0 * 8];
        *(uint4*)&Bs[ra0 * 40 + sa0 * 8] = *(const uint4*)&Bt[(size_t)(n0 + ra0) * K + k0 + sa0 * 8];
        __syncthreads();
        bf8_t a0 = *(const bf8_t*)&As[(wv * 16 + lr) * 40 + quad * 8];
        bf8_t a1 = *(const bf8_t*)&As[((wv + 4) * 16 + lr) * 40 + quad * 8];
#pragma unroll
        for (int nt = 0; nt < 4; ++nt) {
            bf8_t b = *(const bf8_t*)&Bs[(nt * 16 + lr) * 40 + quad * 8];
            acc[0][nt] = __builtin_amdgcn_mfma_f32_16x16x32_bf16(a0, b, acc[0][nt], 0, 0, 0);
            acc[1][nt] = __builtin_amdgcn_mfma_f32_16x16x32_bf16(a1, b, acc[1][nt], 0, 0, 0);
        }
        __syncthreads();
    }
    // bf16 store
#pragma unroll
    for (int si = 0; si < 2; ++si) {
        int mrow = m0 + (wv + si * 4) * 16 + quad * 4;
#pragma unroll
        for (int nt = 0; nt < 4; ++nt) {
            int col = n0 + nt * 16 + lr;
#pragma unroll
            for (int r = 0; r < 4; ++r)
                Cb[(size_t)(mrow + r) * N + col] = __float2bfloat16(acc[si][nt][r]);
        }
    }
    // al partial dots: reduce over this block's 64 cols (one head)
    float asv4[4], adv4[4];
#pragma unroll
    for (int nt = 0; nt < 4; ++nt) {
        asv4[nt] = asv[n0 + nt * 16 + lr];
        adv4[nt] = adv[n0 + nt * 16 + lr];
    }
    int hsel = n0 >> cshift;
#pragma unroll
    for (int si = 0; si < 2; ++si) {
#pragma unroll
        for (int r = 0; r < 4; ++r) {
            float ps = 0.f, pd = 0.f;
#pragma unroll
            for (int nt = 0; nt < 4; ++nt) {
                ps += acc[si][nt][r] * asv4[nt];
                pd += acc[si][nt][r] * adv4[nt];
            }
#pragma unroll
            for (int m = 1; m < 16; m <<= 1) {
                ps += __shfl_xor(ps, m);
                pd += __shfl_xor(pd, m);
            }
            if (lr == 0) {
                int row = m0 + (wv + si * 4) * 16 + quad * 4 + r;
                atomicAdd(&als[row * 4 + hsel], ps);
                atomicAdd(&ald[row * 4 + hsel], pd);
            }
        }
    }
}

// ---- fused per-dst segment softmax (2 passes); writes exp(l-m) + denom ----
__global__ __launch_bounds__(64) void edge_softmax_csr(
        const int* __restrict__ rowptr, const int2* __restrict__ csr_se,
        const float* __restrict__ als, const float* __restrict__ ald,
        const float* __restrict__ eaf, const float* __restrict__ ea_acc,
        const float* __restrict__ sbuf, float* __restrict__ alpha, float* __restrict__ denom) {
    int d = blockIdx.x;
    int lane = threadIdx.x;
    int beg = rowptr[d], end = rowptr[d + 1];
    float ea_mean = ea_acc[0] * (1.0f / N_EDGES);
    float4 ad = *(const float4*)&ald[d * 4];
    float s0 = sbuf[0], s1 = sbuf[1], s2 = sbuf[2], s3 = sbuf[3];
    float m0 = -INFINITY, m1 = -INFINITY, m2 = -INFINITY, m3 = -INFINITY;
    for (int p = beg + lane; p < end; p += 64) {
        int2 se = csr_se[p];
        float eav = (se.y < N_EDGES) ? eaf[se.y] : ea_mean;
        float4 as = *(const float4*)&als[se.x * 4];
        float l0 = as.x + ad.x + eav * s0; l0 = l0 > 0.f ? l0 : 0.2f * l0;
        float l1 = as.y + ad.y + eav * s1; l1 = l1 > 0.f ? l1 : 0.2f * l1;
        float l2 = as.z + ad.z + eav * s2; l2 = l2 > 0.f ? l2 : 0.2f * l2;
        float l3 = as.w + ad.w + eav * s3; l3 = l3 > 0.f ? l3 : 0.2f * l3;
        float4 lv = {l0, l1, l2, l3};
        *(float4*)&alpha[(size_t)p * 4] = lv;
        m0 = fmaxf(m0, l0); m1 = fmaxf(m1, l1); m2 = fmaxf(m2, l2); m3 = fmaxf(m3, l3);
    }
#pragma unroll
    for (int off = 1; off < 64; off <<= 1) {
        m0 = fmaxf(m0, __shfl_xor(m0, off));
        m1 = fmaxf(m1, __shfl_xor(m1, off));
        m2 = fmaxf(m2, __shfl_xor(m2, off));
        m3 = fmaxf(m3, __shfl_xor(m3, off));
    }
    float t0 = 0.f, t1 = 0.f, t2 = 0.f, t3 = 0.f;
    for (int p = beg + lane; p < end; p += 64) {
        float4 lv = *(const float4*)&alpha[(size_t)p * 4];
        lv.x = __expf(lv.x - m0); lv.y = __expf(lv.y - m1);
        lv.z = __expf(lv.z - m2); lv.w = __expf(lv.w - m3);
        *(float4*)&alpha[(size_t)p * 4] = lv;
        t0 += lv.x; t1 += lv.y; t2 += lv.z; t3 += lv.w;
    }
#pragma unroll
    for (int off = 1; off < 64; off <<= 1) {
        t0 += __shfl_xor(t0, off);
        t1 += __shfl_xor(t1, off);
        t2 += __shfl_xor(t2, off);
        t3 += __shfl_xor(t3, off);
    }
    if (lane == 0) {
        float4 dn = {t0, t1, t2, t3};
        *(float4*)&denom[d * 4] = dn;
    }
}

// ---- CSR aggregation over bf16 rows; normalizes by denom; bf16 or fp32 out ----
template <int HC, int C, bool B16OUT>
__global__ __launch_bounds__(HC / 4) void agg_csr_bf(
        const int* __restrict__ rowptr, const int2* __restrict__ csr_se,
        const float* __restrict__ alpha, const float* __restrict__ denom,
        const __hip_bfloat16* __restrict__ hb, void* __restrict__ outb) {
    int d = blockIdx.x;
    int t = threadIdx.x;
    int h = (4 * t) / C;
    float rdn = 1.0f / (denom[d * (HC / C) + h] + 1e-16f);
    float a0 = 0.f, a1 = 0.f, a2 = 0.f, a3 = 0.f;
    int beg = rowptr[d], end = rowptr[d + 1];
    for (int p = beg; p < end; ++p) {
        int2 se = csr_se[p];
        float w = alpha[(size_t)p * 4 + h];
        uint2 raw = *(const uint2*)&hb[(size_t)se.x * HC + 4 * t];
        a0 += w * __uint_as_float(raw.x << 16);
        a1 += w * __uint_as_float(raw.x & 0xFFFF0000u);
        a2 += w * __uint_as_float(raw.y << 16);
        a3 += w * __uint_as_float(raw.y & 0xFFFF0000u);
    }
    a0 *= rdn; a1 *= rdn; a2 *= rdn; a3 *= rdn;
    if (B16OUT) {
        __hip_bfloat16 tmp[4] = {__float2bfloat16(a0), __float2bfloat16(a1),
                                 __float2bfloat16(a2), __float2bfloat16(a3)};
        *(uint2*)&((__hip_bfloat16*)outb)[(size_t)d * HC + 4 * t] = *(uint2*)tmp;
    } else {
        float4 v = {a0, a1, a2, a3};
        *(float4*)&((float*)outb)[(size_t)d * HC + 4 * t] = v;
    }
}

// ---- BN stats over bf16 [N_NODES,512]: 256 thr, 2 ch/thread ----
__global__ __launch_bounds__(256) void bn_part_b(const __hip_bfloat16* __restrict__ x,
                                                 float* __restrict__ musum, float* __restrict__ m2sum) {
    int t = threadIdx.x;
    float s0 = 0.f, s20 = 0.f, s1 = 0.f, s21 = 0.f;
    for (int i = blockIdx.x; i < N_NODES; i += gridDim.x) {
        unsigned u = *(const unsigned*)&x[(size_t)i * 512 + 2 * t];
        float v0 = __uint_as_float(u << 16);
        float v1 = __uint_as_float(u & 0xFFFF0000u);
        s0 += v0; s20 += v0 * v0; s1 += v1; s21 += v1 * v1;
    }
    atomicAdd(&musum[2 * t], s0);
    atomicAdd(&m2sum[2 * t], s20);
    atomicAdd(&musum[2 * t + 1], s1);
    atomicAdd(&m2sum[2 * t + 1], s21);
}

// ---- BN apply + ELU in place on bf16 [N_NODES,512]; mu/rstd inline from sums ----
__global__ __launch_bounds__(256) void bn_apply_elu_b16(__hip_bfloat16* __restrict__ x,
                                                        const float* __restrict__ musum,
                                                        const float* __restrict__ m2sum,
                                                        const float* __restrict__ smalls) {
    int q = blockIdx.x * blockDim.x + threadIdx.x;     // 2,560,000 quads
    if (q >= N_NODES * 512 / 4) return;
    int base = q * 4;
    int j = base & 511;
    uint2 raw = *(uint2*)&x[base];
    float v[4] = {__uint_as_float(raw.x << 16), __uint_as_float(raw.x & 0xFFFF0000u),
                  __uint_as_float(raw.y << 16), __uint_as_float(raw.y & 0xFFFF0000u)};
    __hip_bfloat16 tmp[4];
#pragma unroll
    for (int k = 0; k < 4; ++k) {
        int jj = j + k;
        float m = musum[jj] * (1.0f / N_NODES);
        float var = m2sum[jj] * (1.0f / N_NODES) - m * m;
        float y = smalls[S_G1 + jj] * (v[k] - m) * rsqrtf(var + 1e-5f) + smalls[S_BE1 + jj];
        y = y > 0.f ? y : expm1f(y);
        tmp[k] = __float2bfloat16(y);
    }
    *(uint2*)&x[base] = *(uint2*)tmp;
}

// ---- head mean + BN2 stats ----
__global__ __launch_bounds__(256) void head_mean_stats(const float* __restrict__ ina, float* __restrict__ outb,
                                                       float* __restrict__ musum, float* __restrict__ m2sum) {
    int t = threadIdx.x;
    int c = t & 63, j = t >> 6;
    float ls = 0.f, ls2 = 0.f;
    for (int nd = blockIdx.x * 4 + j; nd < N_NODES; nd += gridDim.x * 4) {
        size_t base = (size_t)nd * 256 + c;
        float s = (ina[base] + ina[base + 64] + ina[base + 128] + ina[base + 192]) * 0.25f;
        outb[(size_t)nd * 64 + c] = s;
        ls += s; ls2 += s * s;
    }
    __shared__ float shs[4][64], sh2[4][64];
    shs[j][c] = ls; sh2[j][c] = ls2;
    __syncthreads();
    if (j == 0) {
        atomicAdd(&musum[c], shs[0][c] + shs[1][c] + shs[2][c] + shs[3][c]);
        atomicAdd(&m2sum[c], sh2[0][c] + sh2[1][c] + sh2[2][c] + sh2[3][c]);
    }
}

// ---- BN apply + ELU fp32 in place [N_NODES,64]; mu/rstd inline ----
__global__ void bn_apply_elu_f32(float* __restrict__ x, const float* __restrict__ musum,
                                 const float* __restrict__ m2sum, const float* __restrict__ smalls) {
    int i = blockIdx.x * blockDim.x + threadIdx.x;
    if (i >= N_NODES * 64) return;
    int j = i & 63;
    float m = musum[j] * (1.0f / N_NODES);
    float var = m2sum[j] * (1.0f / N_NODES) - m * m;
    float y = smalls[S_G2 + j] * (x[i] - m) * rsqrtf(var + 1e-5f) + smalls[S_BE2 + j];
    x[i] = y > 0.f ? y : expm1f(y);
}

// ---- fused pool + MLP: one block per graph ----
__global__ __launch_bounds__(256) void pool_mlp(const float* __restrict__ x, const int* __restrict__ gstart,
                                                const float* __restrict__ smalls, const int* __restrict__ flag,
                                                void* __restrict__ outp) {
    int g = blockIdx.x;
    int t = threadIdx.x;
    int c = t & 63, j = t >> 6;
    int beg = gstart[g], end = gstart[g + 1];
    float s = 0.f;
    for (int i = beg + j; i < end; i += 4)
        s += x[(size_t)i * 64 + c];
    __shared__ float sh[4][64];
    __shared__ float pooled[64];
    __shared__ float hsh[32];
    sh[j][c] = s;
    __syncthreads();
    if (j == 0) {
        float tot = sh[0][c] + sh[1][c] + sh[2][c] + sh[3][c];
        pooled[c] = tot / fmaxf((float)(end - beg), 1.0f);
    }
    __syncthreads();
    if (t < 32) {
        float acc = smalls[S_FB1 + t];
        for (int cc = 0; cc < 64; ++cc)
            acc += pooled[cc] * smalls[S_FW1 + cc * 32 + t];
        hsh[t] = acc > 0.f ? acc : expm1f(acc);
    }
    __syncthreads();
    if (t == 0) {
        float o = smalls[S_FB2];
        for (int k = 0; k < 32; ++k) o += hsh[k] * smalls[S_FW2 + k];
        if (flag[0]) ((float*)outp)[g] = o;
        else ((__hip_bfloat16*)outp)[g] = __float2bfloat16(o);
    }
}

extern "C" void kernel_launch(void* const* d_in, const int* in_sizes, int n_in,
                              void* d_out, int out_size, void* d_ws, size_t ws_size,
                              hipStream_t stream) {
    const void* x    = d_in[0];
    const int* ei    = (const int*)d_in[1];
    const int* batch = (const int*)d_in[2];
    const void* ea   = d_in[3];
    const void* W1   = d_in[4];
    const void* as1  = d_in[5];
    const void* ad1  = d_in[6];
    const void* We1  = d_in[7];
    const void* ae1  = d_in[8];
    const void* g1   = d_in[10];
    const void* be1  = d_in[11];
    const void* W2   = d_in[12];
    const void* as2  = d_in[13];
    const void* ad2  = d_in[14];
    const void* We2  = d_in[15];
    const void* ae2  = d_in[16];
    const void* g2   = d_in[18];
    const void* be2  = d_in[19];
    const void* fw1  = d_in[20];
    const void* fb1  = d_in[21];
    const void* fw2  = d_in[22];
    const void* fb2  = d_in[23];

    char* ws = (char*)d_ws;
    __hip_bfloat16* xb   = (__hip_bfloat16*)(ws + XB_OFF);
    __hip_bfloat16* hb1  = (__hip_bfloat16*)(ws + HB1_OFF);
    __hip_bfloat16* agg1 = (__hip_bfloat16*)(ws + AGG1_OFF);
    __hip_bfloat16* hb2  = (__hip_bfloat16*)(ws + HB2_OFF);
    float* out2a  = (float*)(ws + OUT2A_OFF);
    float* out2   = (float*)(ws + OUT2_OFF);
    float* alpha  = (float*)(ws + ALPHA_OFF);
    float* denom  = (float*)(ws + DENOM_OFF);
    float* eaf    = (float*)(ws + EAF_OFF);
    __hip_bfloat16* W1bt = (__hip_bfloat16*)(ws + W1BT_OFF);
    __hip_bfloat16* W2bt = (__hip_bfloat16*)(ws + W2BT_OFF);
    int2*  csr_se = (int2*)(ws + CSR_OFF);
    int*   rowptr = (int*)(ws + ROWPTR_OFF);
    int*   gstart = (int*)(ws + GSTART_OFF);
    float* smalls = (float*)(ws + SMALL_OFF);
    float* sbuf   = (float*)(ws + SBUF_OFF);
    int*   deg    = (int*)(ws + DEG_OFF);
    int*   cursor = (int*)(ws + CURS_OFF);
    float* als1   = (float*)(ws + ALS1_OFF);
    float* ald1   = (float*)(ws + ALD1_OFF);
    float* als2   = (float*)(ws + ALS2_OFF);
    float* ald2   = (float*)(ws + ALD2_OFF);
    float* musum1 = (float*)(ws + MUSUM1_OFF);
    float* m2sum1 = (float*)(ws + M2SUM1_OFF);
    float* musum2 = (float*)(ws + MUSUM2_OFF);
    float* m2sum2 = (float*)(ws + M2SUM2_OFF);
    int*   flag   = (int*)(ws + FLAGZ_OFF);
    float* ea_acc = (float*)(ws + EAACC_OFF);

    // zero control region + agg1 pad rows (gemm2 A operand)
    hipMemsetAsync(ws + ZERO0_START, 0, ZERO0_SIZE, stream);
    hipMemsetAsync(ws + AGG1_OFF + (size_t)N_NODES * 512 * 2, 0, (MPAD - N_NODES) * 512 * 2, stream);

    detect_dtype<<<256, 256, 0, stream>>>((const unsigned short*)x, flag);
    prep<<<PREP_BLOCKS, 256, 0, stream>>>(flag, x, ea, W1, W2,
                                          as1, ad1, We1, ae1, g1, be1, as2, ad2,
                                          We2, ae2, g2, be2, fw1, fb1, fw2, fb2,
                                          xb, eaf, ea_acc, W1bt, W2bt, smalls, sbuf);

    hist_bounds<<<HIST_BLOCKS + 79, 256, 0, stream>>>(ei, deg, batch, gstart);
    deg_scan<<<1, 1024, 0, stream>>>(deg, rowptr);
    edge_scatter<<<HIST_BLOCKS, 256, 0, stream>>>(ei, rowptr, cursor, csr_se);

    // ---------- layer 1 ----------
    gemm_mfma_al<<<dim3(512 / 64, MPAD / 128), 256, 0, stream>>>(
        (const short*)xb, (const short*)W1bt, hb1, 512, 256,
        als1, ald1, smalls + S_AS1, smalls + S_AD1, 7);
    edge_softmax_csr<<<N_NODES, 64, 0, stream>>>(rowptr, csr_se, als1, ald1, eaf, ea_acc, sbuf, alpha, denom);
    agg_csr_bf<512, 128, true><<<N_NODES, 128, 0, stream>>>(rowptr, csr_se, alpha, denom, hb1, agg1);
    bn_part_b<<<256, 256, 0, stream>>>(agg1, musum1, m2sum1);
    bn_apply_elu_b16<<<10000, 256, 0, stream>>>(agg1, musum1, m2sum1, smalls);

    // ---------- layer 2 ----------
    gemm_mfma_al<<<dim3(256 / 64, MPAD / 128), 256, 0, stream>>>(
        (const short*)agg1, (const short*)W2bt, hb2, 256, 512,
        als2, ald2, smalls + S_AS2, smalls + S_AD2, 6);
    edge_softmax_csr<<<N_NODES, 64, 0, stream>>>(rowptr, csr_se, als2, ald2, eaf, ea_acc, sbuf + 4, alpha, denom);
    agg_csr_bf<256, 64, false><<<N_NODES, 64, 0, stream>>>(rowptr, csr_se, alpha, denom, hb2, out2a);
    head_mean_stats<<<256, 256, 0, stream>>>(out2a, out2, musum2, m2sum2);
    bn_apply_elu_f32<<<(N_NODES * 64 + 255) / 256, 256, 0, stream>>>(out2, musum2, m2sum2, smalls);

    // ---------- pool + MLP ----------
    pool_mlp<<<N_GRAPHS, 256, 0, stream>>>(out2, gstart, smalls, flag, d_out);
}